// Round 12
// baseline (798.837 us; speedup 1.0000x reference)
//
#include <hip/hip_runtime.h>
#include <hip/hip_bf16.h>

// BatchedDiffPool on MI355X. Inputs f32, outputs f32; internal bf16 MFMA.
//
// adj is consumed once (prepass) producing ONLY: den1/den2 and adjm
// (1-bit adjacency mask, 8 MiB). No bf16 attention matrix is ever
// materialized: every adj-sized GEMM operand is GENERATED in staging
// from the mask (+ rank-1 exp weights), which R11 proved is
// cost-equivalent to loading precomputed weights.
//
//  h1=x@We, h2=x@Wa (dual-write) -> f-vectors -> E/F=exp(f),exp(0.2f) ->
//  prepass: den1,den2,adjm ->
//  Y1 = (mask.*w1)@h1t (gen-GEMM, split-K x8) -> zlt = transpose(elu(Y1/den1+h1))
//  Y2 = (mask.*w2)@h2t (gen-GEMM, direct f32) ->
//  s_l = softmax(elu(Y2/den2+h2)) -> d_out(f32)+slb -> slt
//  tT = (mask@slt)^T  (gemm_maskb: LDS-staged binary A, fused transpose)
//  anext = slt@tT ; xnext = slt@zlt (split-K atomics into d_out)

#define DI __device__ __forceinline__

typedef __attribute__((ext_vector_type(8))) short short8;
typedef __attribute__((ext_vector_type(4))) float f32x4;

static DI float bf2f(short s) {
    union { unsigned u; float f; } c;
    c.u = ((unsigned)(unsigned short)s) << 16;
    return c.f;
}
static DI short f2bf(float f) {                       // RTN-even
    union { float f; unsigned u; } c; c.f = f;
    unsigned r = (c.u + 0x7FFFu + ((c.u >> 16) & 1u)) >> 16;
    return (short)(unsigned short)r;
}
// load 8 consecutive elements as bf16 shorts. F32: 0=bf16, 1=f32 RTN
template <int F32>
static DI short8 ld8(const void* base, size_t off) {
    if (F32 == 0) return *(const short8*)((const short*)base + off);
    const float* p = (const float*)base + off;
    f32x4 a = *(const f32x4*)p;
    f32x4 b = *(const f32x4*)(p + 4);
    short8 v;
    #pragma unroll
    for (int e = 0; e < 4; e++) { v[e] = f2bf(a[e]); v[4 + e] = f2bf(b[e]); }
    return v;
}
static DI float wred_sum(float v) {
    #pragma unroll
    for (int o = 32; o > 0; o >>= 1) v += __shfl_down(v, o, 64);
    return v;
}
static DI float wred_max(float v) {
    #pragma unroll
    for (int o = 32; o > 0; o >>= 1) v = fmaxf(v, __shfl_down(v, o, 64));
    return v;
}
// the ONE swizzle definition (16B blocks within each 64-short k-group)
static DI int sfun(int r) { return (r ^ (r >> 3)) & 7; }
static DI int swzk(int k, int r) {
    return (k & ~63) | ((((k >> 3) & 7) ^ sfun(r)) << 3) | (k & 7);
}
static DI unsigned pack2(short lo, short hi) {
    return ((unsigned)(unsigned short)lo) | (((unsigned)(unsigned short)hi) << 16);
}
// async global->LDS, 16B per lane; LDS dest wave-uniform base + lane*16
static DI void gload16(const void* g, void* l) {
    __builtin_amdgcn_global_load_lds(
        (const __attribute__((address_space(1))) unsigned int*)g,
        (__attribute__((address_space(3))) unsigned int*)l, 16, 0, 0);
}

// shared MFMA compute macro (all GEMMs): 2x2 waves, 4x4 fragments
#define MFMA_COMPUTE(Ab_, Bb_)                                                  \
    do {                                                                        \
        _Pragma("unroll")                                                       \
        for (int kk = 0; kk < 2; kk++) {                                        \
            short8 af[4], bq[4];                                                \
            _Pragma("unroll")                                                   \
            for (int m = 0; m < 4; m++) {                                       \
                int ar = wr * 64 + m * 16 + (lane & 15);                        \
                af[m] = *(const short8*)&Ab_[ar]                                \
                            [swzk(kk * 32 + (lane >> 4) * 8, ar)];              \
            }                                                                   \
            _Pragma("unroll")                                                   \
            for (int n = 0; n < 4; n++) {                                       \
                int br = wc * 64 + n * 16 + (lane & 15);                        \
                bq[n] = *(const short8*)&Bb_[br]                                \
                            [swzk(kk * 32 + (lane >> 4) * 8, br)];              \
            }                                                                   \
            _Pragma("unroll")                                                   \
            for (int m = 0; m < 4; m++)                                         \
                _Pragma("unroll")                                               \
                for (int n = 0; n < 4; n++)                                     \
                    acc[m][n] = __builtin_amdgcn_mfma_f32_16x16x32_bf16(        \
                        af[m], bq[n], acc[m][n], 0, 0, 0);                      \
        }                                                                       \
    } while (0)

// ---------------------------------------------------------------------------
// gemm_lds: C = A[M][K] * Bt[N][K]^T, A/Bt bf16 row-major PRE-SWIZZLED,
// lda = ldbt = 8192. 2-phase double-buffered global_load_lds staging.
// EPI: 0 = f32 store, 3 = f32 atomicAdd. kcount/64 EVEN. grid z = k-split.
// ---------------------------------------------------------------------------
template <int EPI, int SWZX>
__launch_bounds__(256)
__global__ void gemm_lds(const short* __restrict__ A, const short* __restrict__ Bt,
                         void* __restrict__ C, int ldc, int kcount) {
    __shared__ short As0[128][64], Bs0[128][64];
    __shared__ short As1[128][64], Bs1[128][64];
    int bx = blockIdx.x, by = blockIdx.y;
    if (SWZX) {
        int lid = blockIdx.x + blockIdx.y * 8;
        int c = lid & 7, s = lid >> 3;
        by = c * 8 + (s >> 3);
        bx = s & 7;
    }
    const int tid  = threadIdx.x;
    const int lane = tid & 63;
    const int w    = tid >> 6;
    const int wr   = w >> 1, wc = w & 1;
    const int i0   = by * 128;
    const int n0   = bx * 128;
    const int k0   = blockIdx.z * kcount;

    const int srow = w * 32 + (lane >> 3);
    const short* gA = A  + (size_t)(i0 + srow) * 8192 + k0 + (lane & 7) * 8;
    const short* gB = Bt + (size_t)(n0 + srow) * 8192 + k0 + (lane & 7) * 8;

    f32x4 acc[4][4];
    #pragma unroll
    for (int m = 0; m < 4; m++)
        #pragma unroll
        for (int n = 0; n < 4; n++) acc[m][n] = (f32x4){0.f, 0.f, 0.f, 0.f};

#define STAGE_TILE(ts, Ab, Bb)                                                  \
    do {                                                                        \
        _Pragma("unroll")                                                       \
        for (int j = 0; j < 4; j++) {                                           \
            gload16(gA + (size_t)(ts) * 64 + (size_t)j * 8 * 8192,              \
                    &Ab[w * 32 + j * 8][0]);                                    \
            gload16(gB + (size_t)(ts) * 64 + (size_t)j * 8 * 8192,              \
                    &Bb[w * 32 + j * 8][0]);                                    \
        }                                                                       \
    } while (0)

    const int nt = kcount >> 6;            // even at every call site
    STAGE_TILE(0, As0, Bs0);
    for (int t = 0; t < nt; t += 2) {
        __syncthreads();
        STAGE_TILE(t + 1, As1, Bs1);
        MFMA_COMPUTE(As0, Bs0);
        __syncthreads();
        if (t + 2 < nt) STAGE_TILE(t + 2, As0, Bs0);
        MFMA_COMPUTE(As1, Bs1);
    }
#undef STAGE_TILE

    #pragma unroll
    for (int m = 0; m < 4; m++) {
        #pragma unroll
        for (int n = 0; n < 4; n++) {
            int row0 = i0 + wr * 64 + m * 16 + ((lane >> 4) << 2);
            int col  = n0 + wc * 64 + n * 16 + (lane & 15);
            #pragma unroll
            for (int r = 0; r < 4; r++) {
                float v = acc[m][n][r];
                if (EPI == 0) ((float*)C)[(size_t)(row0 + r) * ldc + col] = v;
                else atomicAdd(&((float*)C)[(size_t)(row0 + r) * ldc + col], v);
            }
        }
    }
}

// ---------------------------------------------------------------------------
// gemm_gen: C = gen(mask)[M][K] * Bt[N][K]^T with
// a_ik = bit_ik * max(E1[i]E2[k], F1[i]F2[k]). Mask bits from adjm (linear
// order); A staged to LDS swizzled. B via global_load_lds.
// EPI: 0 = f32 store, 3 = f32 atomicAdd. kcount/64 EVEN. grid z = k-split.
// ---------------------------------------------------------------------------
template <int EPI, int SWZX>
__launch_bounds__(256)
__global__ void gemm_gen(const unsigned char* __restrict__ adjm,
                         const short* __restrict__ Bt,
                         float* __restrict__ C, int ldc, int kcount,
                         const float* __restrict__ E1, const float* __restrict__ F1,
                         const float* __restrict__ E2, const float* __restrict__ F2) {
    __shared__ short As0[128][64], Bs0[128][64];
    __shared__ short As1[128][64], Bs1[128][64];
    int bx = blockIdx.x, by = blockIdx.y;
    if (SWZX) {
        int lid = blockIdx.x + blockIdx.y * 8;
        int c = lid & 7, s = lid >> 3;
        by = c * 8 + (s >> 3);
        bx = s & 7;
    }
    const int tid  = threadIdx.x;
    const int lane = tid & 63;
    const int w    = tid >> 6;
    const int wr   = w >> 1, wc = w & 1;
    const int i0   = by * 128;
    const int n0   = bx * 128;
    const int k0   = blockIdx.z * kcount;

    const int srow = w * 32 + (lane >> 3);
    const short* gB = Bt + (size_t)(n0 + srow) * 8192 + k0 + (lane & 7) * 8;
    const int mr = tid >> 1, mh = tid & 1;        // staging row / k-half
    const unsigned char* gM = adjm + (size_t)(i0 + mr) * 1024 + (k0 >> 3) + mh * 4;
    const float e1v = E1[i0 + mr], f1v = F1[i0 + mr];

    f32x4 acc[4][4];
    #pragma unroll
    for (int m = 0; m < 4; m++)
        #pragma unroll
        for (int n = 0; n < 4; n++) acc[m][n] = (f32x4){0.f, 0.f, 0.f, 0.f};

    unsigned mreg;   // 32 mask bits for (mr, k-half)

#define G_ALOAD(ts)                                                             \
    do { mreg = *(const unsigned*)(gM + (size_t)(ts) * 8); } while (0)

#define G_BLOAD(ts, Bb)                                                         \
    do {                                                                        \
        _Pragma("unroll")                                                       \
        for (int j = 0; j < 4; j++)                                             \
            gload16(gB + (size_t)(ts) * 64 + (size_t)j * 8 * 8192,              \
                    &Bb[w * 32 + j * 8][0]);                                    \
    } while (0)

#define G_WSTAGE(ts, As_)                                                       \
    do {                                                                        \
        _Pragma("unroll")                                                       \
        for (int b = 0; b < 4; b++) {                                           \
            int kbr = mh * 4 + b;                                               \
            int rk = k0 + (ts) * 64 + kbr * 8;                                  \
            unsigned mbyte = (mreg >> (8 * b)) & 0xFFu;                         \
            f32x4 e2a = *(const f32x4*)(E2 + rk);                               \
            f32x4 e2b = *(const f32x4*)(E2 + rk + 4);                           \
            f32x4 f2a = *(const f32x4*)(F2 + rk);                               \
            f32x4 f2b = *(const f32x4*)(F2 + rk + 4);                           \
            short8 p;                                                           \
            _Pragma("unroll")                                                   \
            for (int e = 0; e < 8; e++) {                                       \
                float ev = e < 4 ? e2a[e] : e2b[e - 4];                         \
                float fv = e < 4 ? f2a[e] : f2b[e - 4];                         \
                float wg = fmaxf(e1v * ev, f1v * fv);                           \
                p[e] = ((mbyte >> e) & 1) ? f2bf(wg) : (short)0;                \
            }                                                                   \
            *(short8*)&As_[mr][(kbr ^ sfun(mr)) * 8] = p;                       \
        }                                                                       \
    } while (0)

    const int nt = kcount >> 6;            // even
    G_ALOAD(0);
    G_BLOAD(0, Bs0);
    for (int t = 0; t < nt; t += 2) {
        G_WSTAGE(t, As0);
        __syncthreads();
        G_ALOAD(t + 1);
        G_BLOAD(t + 1, Bs1);
        MFMA_COMPUTE(As0, Bs0);
        G_WSTAGE(t + 1, As1);
        __syncthreads();
        if (t + 2 < nt) { G_ALOAD(t + 2); G_BLOAD(t + 2, Bs0); }
        MFMA_COMPUTE(As1, Bs1);
    }
#undef G_ALOAD
#undef G_BLOAD
#undef G_WSTAGE

    #pragma unroll
    for (int m = 0; m < 4; m++) {
        #pragma unroll
        for (int n = 0; n < 4; n++) {
            int row0 = i0 + wr * 64 + m * 16 + ((lane >> 4) << 2);
            int col  = n0 + wc * 64 + n * 16 + (lane & 15);
            #pragma unroll
            for (int r = 0; r < 4; r++) {
                float v = acc[m][n][r];
                if (EPI == 0) C[(size_t)(row0 + r) * ldc + col] = v;
                else atomicAdd(&C[(size_t)(row0 + r) * ldc + col], v);
            }
        }
    }
}

// ---------------------------------------------------------------------------
// gemm_maskb: C^T = (bin(mask)[M][K] @ Bt[N][K]^T)^T. Binary A staged to LDS
// from mask bits (expansion once per element). B via global_load_lds.
// Output bf16 transposed-swizzled (ld 8192). K = 8192 (nt = 128).
// ---------------------------------------------------------------------------
template <int SWZX>
__launch_bounds__(256)
__global__ void gemm_maskb(const unsigned char* __restrict__ adjm,
                           const short* __restrict__ Bt,
                           short* __restrict__ C) {
    __shared__ short As0[128][64], Bs0[128][64];
    __shared__ short As1[128][64], Bs1[128][64];
    int bx = blockIdx.x, by = blockIdx.y;
    if (SWZX) {
        int lid = blockIdx.x + blockIdx.y * 8;
        int c = lid & 7, s = lid >> 3;
        by = c * 8 + (s >> 3);
        bx = s & 7;
    }
    const int tid  = threadIdx.x;
    const int lane = tid & 63;
    const int w    = tid >> 6;
    const int wr   = w >> 1, wc = w & 1;
    const int i0   = by * 128;
    const int n0   = bx * 128;

    const int srow = w * 32 + (lane >> 3);
    const short* gB = Bt + (size_t)(n0 + srow) * 8192 + (lane & 7) * 8;
    const int mr = tid >> 1, mh = tid & 1;
    const unsigned char* gM = adjm + (size_t)(i0 + mr) * 1024 + mh * 4;

    f32x4 acc[4][4];
    #pragma unroll
    for (int m = 0; m < 4; m++)
        #pragma unroll
        for (int n = 0; n < 4; n++) acc[m][n] = (f32x4){0.f, 0.f, 0.f, 0.f};

#define MB_BLOAD(ts, Bb)                                                        \
    do {                                                                        \
        _Pragma("unroll")                                                       \
        for (int j = 0; j < 4; j++)                                             \
            gload16(gB + (size_t)(ts) * 64 + (size_t)j * 8 * 8192,              \
                    &Bb[w * 32 + j * 8][0]);                                    \
    } while (0)

#define MB_WSTAGE(As_, mrg)                                                     \
    do {                                                                        \
        _Pragma("unroll")                                                       \
        for (int b = 0; b < 4; b++) {                                           \
            int kbr = mh * 4 + b;                                               \
            unsigned mbyte = ((mrg) >> (8 * b)) & 0xFFu;                        \
            short8 p;                                                           \
            _Pragma("unroll")                                                   \
            for (int e = 0; e < 8; e++)                                         \
                p[e] = ((mbyte >> e) & 1) ? (short)0x3F80 : (short)0;           \
            *(short8*)&As_[mr][(kbr ^ sfun(mr)) * 8] = p;                       \
        }                                                                       \
    } while (0)

    const int nt = 128;                    // K = 8192
    unsigned mreg = *(const unsigned*)(gM);
    MB_BLOAD(0, Bs0);
    for (int t = 0; t < nt; t += 2) {
        MB_WSTAGE(As0, mreg);
        __syncthreads();
        unsigned mnext = *(const unsigned*)(gM + (size_t)(t + 1) * 8);
        MB_BLOAD(t + 1, Bs1);
        MFMA_COMPUTE(As0, Bs0);
        MB_WSTAGE(As1, mnext);
        __syncthreads();
        if (t + 2 < nt) {
            mreg = *(const unsigned*)(gM + (size_t)(t + 2) * 8);
            MB_BLOAD(t + 2, Bs0);
        }
        MFMA_COMPUTE(As1, Bs1);
    }
#undef MB_BLOAD
#undef MB_WSTAGE

    // transposed-swizzled bf16 epilogue (C^T)
    #pragma unroll
    for (int m = 0; m < 4; m++) {
        #pragma unroll
        for (int n = 0; n < 4; n++) {
            int row0 = i0 + wr * 64 + m * 16 + ((lane >> 4) << 2);
            int col  = n0 + wc * 64 + n * 16 + (lane & 15);
            unsigned long long pk = 0;
            #pragma unroll
            for (int r = 0; r < 4; r++)
                pk |= (unsigned long long)(unsigned short)f2bf(acc[m][n][r])
                      << (16 * r);
            *(unsigned long long*)(C + (size_t)col * 8192 + swzk(row0, col)) = pk;
        }
    }
}

// ---------------------------------------------------------------------------
// gemm_xw_k: C[M][N]=A[M][256]@B[256][N], A,B f32. Dual-write epilogue:
// C row-major bf16 (ld=N) + Ct = C^T bf16 swizzled (ld=8192).
// ---------------------------------------------------------------------------
template <int SWZX>
__launch_bounds__(256)
__global__ void gemm_xw_k(const float* __restrict__ A, const float* __restrict__ B,
                          short* __restrict__ C, short* __restrict__ Ct, int ldn) {
    __shared__ short As[128][64];
    __shared__ short Bs[128][64];
    int bx = blockIdx.x, by = blockIdx.y;
    if (SWZX) {
        int lid = blockIdx.x + blockIdx.y * 8;
        int c = lid & 7, s = lid >> 3;
        by = c * 8 + (s >> 3);
        bx = s & 7;
    }
    const int tid  = threadIdx.x;
    const int lane = tid & 63;
    const int w    = tid >> 6;
    const int wr   = w >> 1, wc = w & 1;
    const int i0   = by * 128;
    const int n0   = bx * 128;

    f32x4 acc[4][4];
    #pragma unroll
    for (int m = 0; m < 4; m++)
        #pragma unroll
        for (int n = 0; n < 4; n++) acc[m][n] = (f32x4){0.f, 0.f, 0.f, 0.f};

    for (int ks = 0; ks < 256; ks += 64) {
        __syncthreads();
        #pragma unroll
        for (int it = 0; it < 4; it++) {
            int idx = it * 256 + tid;
            int cg = idx & 7, r = idx >> 3;
            *(short8*)&As[r][swzk(cg * 8, r)] =
                ld8<1>(A, (size_t)(i0 + r) * 256 + ks + cg * 8);
        }
        #pragma unroll
        for (int it = 0; it < 2; it++) {
            int idx = it * 256 + tid;
            int ng = idx & 15, kp = idx >> 4;
            int k = 2 * kp;
            short8 r0 = ld8<1>(B, (size_t)(ks + k) * ldn + n0 + ng * 8);
            short8 r1 = ld8<1>(B, (size_t)(ks + k + 1) * ldn + n0 + ng * 8);
            #pragma unroll
            for (int j = 0; j < 8; j++) {
                int row = ng * 8 + j;
                *(unsigned*)&Bs[row][swzk(k, row)] = pack2(r0[j], r1[j]);
            }
        }
        __syncthreads();
        MFMA_COMPUTE(As, Bs);
    }
    #pragma unroll
    for (int m = 0; m < 4; m++) {
        #pragma unroll
        for (int n = 0; n < 4; n++) {
            int row0 = i0 + wr * 64 + m * 16 + ((lane >> 4) << 2);
            int col  = n0 + wc * 64 + n * 16 + (lane & 15);
            unsigned long long pk = 0;
            #pragma unroll
            for (int r = 0; r < 4; r++) {
                short b = f2bf(acc[m][n][r]);
                C[(size_t)(row0 + r) * ldn + col] = b;
                pk |= (unsigned long long)(unsigned short)b << (16 * r);
            }
            *(unsigned long long*)(Ct + (size_t)col * 8192 + swzk(row0, col)) = pk;
        }
    }
}

// f1g[i] = h_g[i,:] . a_g[:F], f2g[i] = h_g[i,:] . a_g[F:]
__launch_bounds__(256)
__global__ void compute_f_k(const short* __restrict__ h1, const short* __restrict__ h2,
                            const float* __restrict__ ae, const float* __restrict__ aa,
                            float* __restrict__ f11, float* __restrict__ f21,
                            float* __restrict__ f12, float* __restrict__ f22) {
    int row = blockIdx.x, t = threadIdx.x;
    float s11 = 0.f, s21 = 0.f, s12 = 0.f, s22 = 0.f;
    if (t < 128) {
        float hv = bf2f(h1[(size_t)row * 128 + t]);
        s11 = hv * ae[t];
        s21 = hv * ae[128 + t];
    }
    #pragma unroll
    for (int q = 0; q < 4; q++) {
        int f = t + q * 256;
        float hv = bf2f(h2[(size_t)row * 1024 + f]);
        s12 += hv * aa[f];
        s22 += hv * aa[1024 + f];
    }
    __shared__ float red[4][4];
    s11 = wred_sum(s11); s21 = wred_sum(s21);
    s12 = wred_sum(s12); s22 = wred_sum(s22);
    int w = t >> 6;
    if ((t & 63) == 0) { red[0][w] = s11; red[1][w] = s21; red[2][w] = s12; red[3][w] = s22; }
    __syncthreads();
    if (t == 0) {
        f11[row] = red[0][0] + red[0][1] + red[0][2] + red[0][3];
        f21[row] = red[1][0] + red[1][1] + red[1][2] + red[1][3];
        f12[row] = red[2][0] + red[2][1] + red[2][2] + red[2][3];
        f22[row] = red[3][0] + red[3][1] + red[3][2] + red[3][3];
    }
}

// E/F vectors: E = exp(f), F = exp(0.2 f)
__launch_bounds__(256)
__global__ void evec_k(const float* __restrict__ f11, const float* __restrict__ f21,
                       const float* __restrict__ f12, const float* __restrict__ f22,
                       float* __restrict__ E11, float* __restrict__ F11,
                       float* __restrict__ E21, float* __restrict__ F21,
                       float* __restrict__ E12, float* __restrict__ F12,
                       float* __restrict__ E22, float* __restrict__ F22) {
    int i = blockIdx.x * 256 + threadIdx.x;
    if (i >= 8192) return;
    float a = f11[i], b = f21[i], c = f12[i], d = f22[i];
    E11[i] = __expf(a); F11[i] = __expf(0.2f * a);
    E21[i] = __expf(b); F21[i] = __expf(0.2f * b);
    E12[i] = __expf(c); F12[i] = __expf(0.2f * c);
    E22[i] = __expf(d); F22[i] = __expf(0.2f * d);
}

// One adj pass, 4 rows/block: den1/den2 + adjm (bitmask). ONLY 8 MB written.
__launch_bounds__(256)
__global__ void prepass_k(const float* __restrict__ adj,
                          const float* __restrict__ E11, const float* __restrict__ F11,
                          const float* __restrict__ E21, const float* __restrict__ F21,
                          const float* __restrict__ E12, const float* __restrict__ F12,
                          const float* __restrict__ E22, const float* __restrict__ F22,
                          float* __restrict__ den1, float* __restrict__ den2,
                          unsigned char* __restrict__ adjm) {
    const int r0 = blockIdx.x * 4, t = threadIdx.x;
    float e1r[4], f1r[4], e2r[4], f2r[4];
    #pragma unroll
    for (int r = 0; r < 4; r++) {
        e1r[r] = E11[r0 + r]; f1r[r] = F11[r0 + r];
        e2r[r] = E12[r0 + r]; f2r[r] = F12[r0 + r];
    }
    float d1[4] = {0.f, 0.f, 0.f, 0.f}, d2[4] = {0.f, 0.f, 0.f, 0.f};
    #pragma unroll
    for (int jc = 0; jc < 4; jc++) {
        int jb = jc * 2048 + t * 8;
        f32x4 eA0 = *(const f32x4*)(E21 + jb), eA1 = *(const f32x4*)(E21 + jb + 4);
        f32x4 fA0 = *(const f32x4*)(F21 + jb), fA1 = *(const f32x4*)(F21 + jb + 4);
        f32x4 eB0 = *(const f32x4*)(E22 + jb), eB1 = *(const f32x4*)(E22 + jb + 4);
        f32x4 fB0 = *(const f32x4*)(F22 + jb), fB1 = *(const f32x4*)(F22 + jb + 4);
        #pragma unroll
        for (int r = 0; r < 4; r++) {
            const float* ap = adj + (size_t)(r0 + r) * 8192 + jb;
            f32x4 a0 = *(const f32x4*)ap, a1 = *(const f32x4*)(ap + 4);
            unsigned mb = 0;
            #pragma unroll
            for (int e = 0; e < 8; e++) {
                float av = e < 4 ? a0[e] : a1[e - 4];
                float eA = e < 4 ? eA0[e] : eA1[e - 4];
                float fA = e < 4 ? fA0[e] : fA1[e - 4];
                float eB = e < 4 ? eB0[e] : eB1[e - 4];
                float fB = e < 4 ? fB0[e] : fB1[e - 4];
                float x1 = fmaxf(e1r[r] * eA, f1r[r] * fA);  // exp(lrelu(f1+f2))
                float x2 = fmaxf(e2r[r] * eB, f2r[r] * fB);
                bool on = av > 0.f;
                d1[r] += on ? x1 : 0.f;
                d2[r] += on ? x2 : 0.f;
                mb |= (on ? 1u : 0u) << e;
            }
            adjm[(size_t)(r0 + r) * 1024 + (jb >> 3)] = (unsigned char)mb;
        }
    }
    __shared__ float r1s[4][4], r2s[4][4];   // [wave][row]
    #pragma unroll
    for (int r = 0; r < 4; r++) { d1[r] = wred_sum(d1[r]); d2[r] = wred_sum(d2[r]); }
    if ((t & 63) == 0) {
        #pragma unroll
        for (int r = 0; r < 4; r++) { r1s[t >> 6][r] = d1[r]; r2s[t >> 6][r] = d2[r]; }
    }
    __syncthreads();
    if (t < 4) {
        den1[r0 + t] = r1s[0][t] + r1s[1][t] + r1s[2][t] + r1s[3][t];
        den2[r0 + t] = r2s[0][t] + r2s[1][t] + r2s[2][t] + r2s[3][t];
    }
}

// zlt = transpose(elu(Y1/den1 + h1)) swizzled, fused. Block = 64 rows x 128 cols.
__launch_bounds__(256)
__global__ void epi_gat1t_k(const float* __restrict__ Y1, const float* __restrict__ den1,
                            const short* __restrict__ h1, short* __restrict__ zlt) {
    __shared__ short ts[128][65];
    int tr = blockIdx.x * 64;
    int t = threadIdx.x;
    #pragma unroll
    for (int it = 0; it < 4; it++) {
        int idx = it * 256 + t;
        int r = idx >> 4, cb = idx & 15;
        int row = tr + r;
        float d = den1[row]; d = d > 0.f ? d : 1.f;
        const float* yp = Y1 + (size_t)row * 128 + cb * 8;
        f32x4 y0 = *(const f32x4*)yp, y1 = *(const f32x4*)(yp + 4);
        short8 hv = *(const short8*)(h1 + (size_t)row * 128 + cb * 8);
        #pragma unroll
        for (int e = 0; e < 8; e++) {
            float z = (e < 4 ? y0[e] : y1[e - 4]) / d + bf2f(hv[e]);
            z = z > 0.f ? z : (__expf(z) - 1.f);
            ts[cb * 8 + e][r] = f2bf(z);
        }
    }
    __syncthreads();
    #pragma unroll
    for (int it = 0; it < 4; it++) {
        int idx = it * 256 + t;
        int c = idx >> 3, rb = idx & 7;
        short8 v = *(const short8*)&ts[c][rb * 8];
        *(short8*)(zlt + (size_t)c * 8192 + tr + ((rb ^ sfun(c)) << 3)) = v;
    }
}

// s_l row = softmax( elu(Y2/den2 + h2) ). f32 to d_out, bf16 row-major to ws.
__launch_bounds__(256)
__global__ void episoft_k(const float* __restrict__ Y2, const float* __restrict__ den2,
                          const short* __restrict__ h2, float* __restrict__ slo,
                          short* __restrict__ slb) {
    int row = blockIdx.x, t = threadIdx.x;
    float d = den2[row];
    d = d > 0.f ? d : 1.f;
    float v[4], mx = -1e30f;
    #pragma unroll
    for (int q = 0; q < 4; q++) {
        int j = t + q * 256;
        float a = Y2[(size_t)row * 1024 + j] / d + bf2f(h2[(size_t)row * 1024 + j]);
        a = a > 0.f ? a : (__expf(a) - 1.f);
        v[q] = a;
        mx = fmaxf(mx, a);
    }
    __shared__ float sred[4];
    __shared__ float sbc;
    mx = wred_max(mx);
    if ((t & 63) == 0) sred[t >> 6] = mx;
    __syncthreads();
    if (t == 0) sbc = fmaxf(fmaxf(sred[0], sred[1]), fmaxf(sred[2], sred[3]));
    __syncthreads();
    mx = sbc;
    float s = 0.f;
    #pragma unroll
    for (int q = 0; q < 4; q++) { v[q] = __expf(v[q] - mx); s += v[q]; }
    s = wred_sum(s);
    if ((t & 63) == 0) sred[t >> 6] = s;
    __syncthreads();
    if (t == 0) sbc = sred[0] + sred[1] + sred[2] + sred[3];
    __syncthreads();
    float inv = 1.f / sbc;
    #pragma unroll
    for (int q = 0; q < 4; q++) {
        float sv = v[q] * inv;
        slo[(size_t)row * 1024 + t + q * 256] = sv;
        slb[(size_t)row * 1024 + t + q * 256] = f2bf(sv);
    }
}

// tiled transpose: in [R][C] bf16 -> out [C][R] bf16, swizzled blocks
template <int F32IN>
__launch_bounds__(256)
__global__ void transpose_swz_k(const void* __restrict__ in, short* __restrict__ out,
                                int R, int C) {
    __shared__ short ts[64][72];
    int tc = blockIdx.x * 64;
    int tr = blockIdx.y * 64;
    int t = threadIdx.x;
    #pragma unroll
    for (int h = 0; h < 2; h++) {
        int r = (t >> 3) + h * 32, c = (t & 7) * 8;
        *(short8*)&ts[r][c] = ld8<F32IN>(in, (size_t)(tr + r) * C + tc + c);
    }
    __syncthreads();
    #pragma unroll
    for (int h = 0; h < 2; h++) {
        int n = t >> 2, blk = (t & 3) + h * 4;
        short8 v;
        #pragma unroll
        for (int e = 0; e < 8; e++) v[e] = ts[blk * 8 + e][n];
        *(short8*)(out + (size_t)(tc + n) * R + tr + ((blk ^ sfun(tc + n)) << 3)) = v;
    }
}

extern "C" void kernel_launch(void* const* d_in, const int* in_sizes, int n_in,
                              void* d_out, int out_size, void* d_ws, size_t ws_size,
                              hipStream_t stream) {
    const float* x   = (const float*)d_in[0];  // [8192,256]
    const float* adj = (const float*)d_in[1];  // [8192,8192]
    const float* We  = (const float*)d_in[2];  // [256,128]
    const float* ae  = (const float*)d_in[3];  // [256]
    const float* Wa  = (const float*)d_in[4];  // [256,1024]
    const float* aa  = (const float*)d_in[5];  // [2048]
    float* out = (float*)d_out;

    char* w = (char*)d_ws;                       // ~136 MiB used
    short* h1b = (short*)(w);                    // 0..2M    bf16 [8192,128]
    short* h2b = (short*)(w + (2u   << 20));     // 2..18M   bf16 [8192,1024]
    float* f11 = (float*)(w + (18u  << 20));     // 18..19M  vectors
    float* f21 = f11 + 8192;  float* f12 = f21 + 8192; float* f22 = f12 + 8192;
    float* den1 = f22 + 8192; float* den2 = den1 + 8192;
    float* E11 = den2 + 8192; float* F11 = E11 + 8192;
    float* E21 = F11 + 8192;  float* F21 = E21 + 8192;
    float* E12 = F21 + 8192;  float* F12 = E12 + 8192;
    float* E22 = F12 + 8192;  float* F22 = E22 + 8192;
    float* Y1f = (float*)(w + (21u << 20));      // 21..25M  f32  [8192,128]
    float* Y2f = (float*)(w + (25u << 20));      // 25..57M  f32  [8192,1024]
    short* slb = (short*)(w + (57u << 20));      // 57..73M  bf16 [8192,1024]
    short* h1t = (short*)(w + (73u << 20));      // 73..75M  bf16 [128,8192]  swz
    short* h2t = (short*)(w + (75u << 20));      // 75..91M  bf16 [1024,8192] swz
    short* slt = (short*)(w + (91u << 20));      // 91..107M bf16 [1024,8192] swz
    short* zlt = (short*)(w + (107u << 20));     // 107..109M bf16 [128,8192] swz
    short* tT  = (short*)(w + (109u << 20));     // 109..125M bf16 [1024,8192] swz
    unsigned char* adjm = (unsigned char*)(w + (128u << 20)); // 8 MiB bitmask

    float* xo  = out;                            // xnext [1024,128]
    float* ao  = out + 131072;                   // anext [1024,1024]
    float* slo = out + 131072 + 1048576;         // s_l   [8192,1024]

    hipMemsetAsync(out, 0, (size_t)(131072 + 1048576) * 4, stream);
    hipMemsetAsync(Y1f, 0, (size_t)8192 * 128 * 4, stream);

    // h1 = x@We ; h2 = x@Wa  (dual write: row-major + transposed-swizzled)
    gemm_xw_k<0><<<dim3(1, 64), 256, 0, stream>>>(x, We, h1b, h1t, 128);
    gemm_xw_k<1><<<dim3(8, 64), 256, 0, stream>>>(x, Wa, h2b, h2t, 1024);
    compute_f_k<<<dim3(8192), 256, 0, stream>>>(h1b, h2b, ae, aa, f11, f21, f12, f22);
    evec_k<<<dim3(32), 256, 0, stream>>>(f11, f21, f12, f22,
        E11, F11, E21, F21, E12, F12, E22, F22);
    prepass_k<<<dim3(2048), 256, 0, stream>>>(adj,
        E11, F11, E21, F21, E12, F12, E22, F22, den1, den2, adjm);

    // Y1 = (mask .* w1) @ h1 (gen-GEMM, split-K x8, atomics into Y1f)
    gemm_gen<3, 0><<<dim3(1, 64, 8), 256, 0, stream>>>(
        adjm, h1t, Y1f, 128, 1024, E11, F11, E21, F21);
    epi_gat1t_k<<<dim3(128), 256, 0, stream>>>(Y1f, den1, h1b, zlt);

    // Y2 = (mask .* w2) @ h2 (gen-GEMM, unsplit, direct f32 store)
    gemm_gen<0, 1><<<dim3(8, 64, 1), 256, 0, stream>>>(
        adjm, h2t, Y2f, 1024, 8192, E12, F12, E22, F22);
    episoft_k<<<dim3(8192), 256, 0, stream>>>(Y2f, den2, h2b, slo, slb);
    transpose_swz_k<0><<<dim3(16, 128), 256, 0, stream>>>(slb, slt, 8192, 1024);

    // tT = (mask @ s_l)^T  (LDS-staged binary A, fused transpose)
    gemm_maskb<1><<<dim3(8, 64), 256, 0, stream>>>(adjm, slt, tT);

    // anext = s_l^T @ t ; xnext = s_l^T @ z_l  (atomics into d_out)
    gemm_lds<3, 0><<<dim3(8, 8, 8), 256, 0, stream>>>(slt, tT, ao, 1024, 1024);
    gemm_lds<3, 0><<<dim3(1, 8, 32), 256, 0, stream>>>(slt, zlt, xo, 128, 256);
}

// Round 13
// 647.704 us; speedup vs baseline: 1.2333x; 1.2333x over previous
//
#include <hip/hip_runtime.h>
#include <hip/hip_bf16.h>

// BatchedDiffPool on MI355X. Inputs f32, outputs f32; internal bf16 MFMA.
// R11 configuration (best verified: 657 us) + bf16 Y2 intermediate.
//
//  h1=x@We, h2=x@Wa (dual-write) -> f-vectors -> E/F=exp(f),exp(0.2f) ->
//  prepass: den1,den2,P2b(bf16 swz),adjm(bitmask) ->
//  Y1 = (mask.*w1)@h1t (gen-GEMM, split-K x8) -> zlt = transpose(elu(Y1/den1+h1))
//  Y2 = P2b@h2t (gload GEMM, bf16 out) ->
//  s_l = softmax(elu(Y2/den2+h2)) -> d_out(f32)+slb -> slt
//  tT = (mask@slt)^T  (gemm_maskb: LDS-staged binary A, fused transpose)
//  anext = slt@tT ; xnext = slt@zlt (split-K atomics into d_out)

#define DI __device__ __forceinline__

typedef __attribute__((ext_vector_type(8))) short short8;
typedef __attribute__((ext_vector_type(4))) float f32x4;

static DI float bf2f(short s) {
    union { unsigned u; float f; } c;
    c.u = ((unsigned)(unsigned short)s) << 16;
    return c.f;
}
static DI short f2bf(float f) {                       // RTN-even
    union { float f; unsigned u; } c; c.f = f;
    unsigned r = (c.u + 0x7FFFu + ((c.u >> 16) & 1u)) >> 16;
    return (short)(unsigned short)r;
}
// load 8 consecutive elements as bf16 shorts. F32: 0=bf16, 1=f32 RTN
template <int F32>
static DI short8 ld8(const void* base, size_t off) {
    if (F32 == 0) return *(const short8*)((const short*)base + off);
    const float* p = (const float*)base + off;
    f32x4 a = *(const f32x4*)p;
    f32x4 b = *(const f32x4*)(p + 4);
    short8 v;
    #pragma unroll
    for (int e = 0; e < 4; e++) { v[e] = f2bf(a[e]); v[4 + e] = f2bf(b[e]); }
    return v;
}
static DI float wred_sum(float v) {
    #pragma unroll
    for (int o = 32; o > 0; o >>= 1) v += __shfl_down(v, o, 64);
    return v;
}
static DI float wred_max(float v) {
    #pragma unroll
    for (int o = 32; o > 0; o >>= 1) v = fmaxf(v, __shfl_down(v, o, 64));
    return v;
}
// the ONE swizzle definition (16B blocks within each 64-short k-group)
static DI int sfun(int r) { return (r ^ (r >> 3)) & 7; }
static DI int swzk(int k, int r) {
    return (k & ~63) | ((((k >> 3) & 7) ^ sfun(r)) << 3) | (k & 7);
}
static DI unsigned pack2(short lo, short hi) {
    return ((unsigned)(unsigned short)lo) | (((unsigned)(unsigned short)hi) << 16);
}
// async global->LDS, 16B per lane; LDS dest wave-uniform base + lane*16
static DI void gload16(const void* g, void* l) {
    __builtin_amdgcn_global_load_lds(
        (const __attribute__((address_space(1))) unsigned int*)g,
        (__attribute__((address_space(3))) unsigned int*)l, 16, 0, 0);
}

// shared MFMA compute macro (all GEMMs): 2x2 waves, 4x4 fragments
#define MFMA_COMPUTE(Ab_, Bb_)                                                  \
    do {                                                                        \
        _Pragma("unroll")                                                       \
        for (int kk = 0; kk < 2; kk++) {                                        \
            short8 af[4], bq[4];                                                \
            _Pragma("unroll")                                                   \
            for (int m = 0; m < 4; m++) {                                       \
                int ar = wr * 64 + m * 16 + (lane & 15);                        \
                af[m] = *(const short8*)&Ab_[ar]                                \
                            [swzk(kk * 32 + (lane >> 4) * 8, ar)];              \
            }                                                                   \
            _Pragma("unroll")                                                   \
            for (int n = 0; n < 4; n++) {                                       \
                int br = wc * 64 + n * 16 + (lane & 15);                        \
                bq[n] = *(const short8*)&Bb_[br]                                \
                            [swzk(kk * 32 + (lane >> 4) * 8, br)];              \
            }                                                                   \
            _Pragma("unroll")                                                   \
            for (int m = 0; m < 4; m++)                                         \
                _Pragma("unroll")                                               \
                for (int n = 0; n < 4; n++)                                     \
                    acc[m][n] = __builtin_amdgcn_mfma_f32_16x16x32_bf16(        \
                        af[m], bq[n], acc[m][n], 0, 0, 0);                      \
        }                                                                       \
    } while (0)

// ---------------------------------------------------------------------------
// gemm_lds: C = A[M][K] * Bt[N][K]^T, A/Bt bf16 row-major PRE-SWIZZLED,
// lda = ldbt = 8192. 2-phase double-buffered global_load_lds staging.
// EPI: 0 = f32 store, 2 = bf16 row-major store, 3 = f32 atomicAdd.
// kcount/64 EVEN. grid z = k-split.
// ---------------------------------------------------------------------------
template <int EPI, int SWZX>
__launch_bounds__(256)
__global__ void gemm_lds(const short* __restrict__ A, const short* __restrict__ Bt,
                         void* __restrict__ C, int ldc, int kcount) {
    __shared__ short As0[128][64], Bs0[128][64];
    __shared__ short As1[128][64], Bs1[128][64];
    int bx = blockIdx.x, by = blockIdx.y;
    if (SWZX) {
        int lid = blockIdx.x + blockIdx.y * 8;
        int c = lid & 7, s = lid >> 3;
        by = c * 8 + (s >> 3);
        bx = s & 7;
    }
    const int tid  = threadIdx.x;
    const int lane = tid & 63;
    const int w    = tid >> 6;
    const int wr   = w >> 1, wc = w & 1;
    const int i0   = by * 128;
    const int n0   = bx * 128;
    const int k0   = blockIdx.z * kcount;

    const int srow = w * 32 + (lane >> 3);
    const short* gA = A  + (size_t)(i0 + srow) * 8192 + k0 + (lane & 7) * 8;
    const short* gB = Bt + (size_t)(n0 + srow) * 8192 + k0 + (lane & 7) * 8;

    f32x4 acc[4][4];
    #pragma unroll
    for (int m = 0; m < 4; m++)
        #pragma unroll
        for (int n = 0; n < 4; n++) acc[m][n] = (f32x4){0.f, 0.f, 0.f, 0.f};

#define STAGE_TILE(ts, Ab, Bb)                                                  \
    do {                                                                        \
        _Pragma("unroll")                                                       \
        for (int j = 0; j < 4; j++) {                                           \
            gload16(gA + (size_t)(ts) * 64 + (size_t)j * 8 * 8192,              \
                    &Ab[w * 32 + j * 8][0]);                                    \
            gload16(gB + (size_t)(ts) * 64 + (size_t)j * 8 * 8192,              \
                    &Bb[w * 32 + j * 8][0]);                                    \
        }                                                                       \
    } while (0)

    const int nt = kcount >> 6;            // even at every call site
    STAGE_TILE(0, As0, Bs0);
    for (int t = 0; t < nt; t += 2) {
        __syncthreads();
        STAGE_TILE(t + 1, As1, Bs1);
        MFMA_COMPUTE(As0, Bs0);
        __syncthreads();
        if (t + 2 < nt) STAGE_TILE(t + 2, As0, Bs0);
        MFMA_COMPUTE(As1, Bs1);
    }
#undef STAGE_TILE

    #pragma unroll
    for (int m = 0; m < 4; m++) {
        #pragma unroll
        for (int n = 0; n < 4; n++) {
            int row0 = i0 + wr * 64 + m * 16 + ((lane >> 4) << 2);
            int col  = n0 + wc * 64 + n * 16 + (lane & 15);
            #pragma unroll
            for (int r = 0; r < 4; r++) {
                float v = acc[m][n][r];
                if (EPI == 0)      ((float*)C)[(size_t)(row0 + r) * ldc + col] = v;
                else if (EPI == 2) ((short*)C)[(size_t)(row0 + r) * ldc + col] = f2bf(v);
                else atomicAdd(&((float*)C)[(size_t)(row0 + r) * ldc + col], v);
            }
        }
    }
}

// ---------------------------------------------------------------------------
// gemm_gen: C = gen(mask)[M][K] * Bt[N][K]^T with
// a_ik = bit_ik * max(E1[i]E2[k], F1[i]F2[k]). Mask bits from adjm; A staged
// to LDS swizzled. B via global_load_lds. EPI=3 atomicAdd. kcount/64 EVEN.
// (Use ONLY where the A-panel is consumed by ONE n-block — R12 lesson.)
// ---------------------------------------------------------------------------
template <int EPI, int SWZX>
__launch_bounds__(256)
__global__ void gemm_gen(const unsigned char* __restrict__ adjm,
                         const short* __restrict__ Bt,
                         float* __restrict__ C, int ldc, int kcount,
                         const float* __restrict__ E1, const float* __restrict__ F1,
                         const float* __restrict__ E2, const float* __restrict__ F2) {
    __shared__ short As0[128][64], Bs0[128][64];
    __shared__ short As1[128][64], Bs1[128][64];
    int bx = blockIdx.x, by = blockIdx.y;
    if (SWZX) {
        int lid = blockIdx.x + blockIdx.y * 8;
        int c = lid & 7, s = lid >> 3;
        by = c * 8 + (s >> 3);
        bx = s & 7;
    }
    const int tid  = threadIdx.x;
    const int lane = tid & 63;
    const int w    = tid >> 6;
    const int wr   = w >> 1, wc = w & 1;
    const int i0   = by * 128;
    const int n0   = bx * 128;
    const int k0   = blockIdx.z * kcount;

    const int srow = w * 32 + (lane >> 3);
    const short* gB = Bt + (size_t)(n0 + srow) * 8192 + k0 + (lane & 7) * 8;
    const int mr = tid >> 1, mh = tid & 1;        // staging row / k-half
    const unsigned char* gM = adjm + (size_t)(i0 + mr) * 1024 + (k0 >> 3) + mh * 4;
    const float e1v = E1[i0 + mr], f1v = F1[i0 + mr];

    f32x4 acc[4][4];
    #pragma unroll
    for (int m = 0; m < 4; m++)
        #pragma unroll
        for (int n = 0; n < 4; n++) acc[m][n] = (f32x4){0.f, 0.f, 0.f, 0.f};

    unsigned mreg;   // 32 mask bits for (mr, k-half)

#define G_ALOAD(ts)                                                             \
    do { mreg = *(const unsigned*)(gM + (size_t)(ts) * 8); } while (0)

#define G_BLOAD(ts, Bb)                                                         \
    do {                                                                        \
        _Pragma("unroll")                                                       \
        for (int j = 0; j < 4; j++)                                             \
            gload16(gB + (size_t)(ts) * 64 + (size_t)j * 8 * 8192,              \
                    &Bb[w * 32 + j * 8][0]);                                    \
    } while (0)

#define G_WSTAGE(ts, As_)                                                       \
    do {                                                                        \
        _Pragma("unroll")                                                       \
        for (int b = 0; b < 4; b++) {                                           \
            int kbr = mh * 4 + b;                                               \
            int rk = k0 + (ts) * 64 + kbr * 8;                                  \
            unsigned mbyte = (mreg >> (8 * b)) & 0xFFu;                         \
            f32x4 e2a = *(const f32x4*)(E2 + rk);                               \
            f32x4 e2b = *(const f32x4*)(E2 + rk + 4);                           \
            f32x4 f2a = *(const f32x4*)(F2 + rk);                               \
            f32x4 f2b = *(const f32x4*)(F2 + rk + 4);                           \
            short8 p;                                                           \
            _Pragma("unroll")                                                   \
            for (int e = 0; e < 8; e++) {                                       \
                float ev = e < 4 ? e2a[e] : e2b[e - 4];                         \
                float fv = e < 4 ? f2a[e] : f2b[e - 4];                         \
                float wg = fmaxf(e1v * ev, f1v * fv);                           \
                p[e] = ((mbyte >> e) & 1) ? f2bf(wg) : (short)0;                \
            }                                                                   \
            *(short8*)&As_[mr][(kbr ^ sfun(mr)) * 8] = p;                       \
        }                                                                       \
    } while (0)

    const int nt = kcount >> 6;            // even
    G_ALOAD(0);
    G_BLOAD(0, Bs0);
    for (int t = 0; t < nt; t += 2) {
        G_WSTAGE(t, As0);
        __syncthreads();
        G_ALOAD(t + 1);
        G_BLOAD(t + 1, Bs1);
        MFMA_COMPUTE(As0, Bs0);
        G_WSTAGE(t + 1, As1);
        __syncthreads();
        if (t + 2 < nt) { G_ALOAD(t + 2); G_BLOAD(t + 2, Bs0); }
        MFMA_COMPUTE(As1, Bs1);
    }
#undef G_ALOAD
#undef G_BLOAD
#undef G_WSTAGE

    #pragma unroll
    for (int m = 0; m < 4; m++) {
        #pragma unroll
        for (int n = 0; n < 4; n++) {
            int row0 = i0 + wr * 64 + m * 16 + ((lane >> 4) << 2);
            int col  = n0 + wc * 64 + n * 16 + (lane & 15);
            #pragma unroll
            for (int r = 0; r < 4; r++)
                atomicAdd(&C[(size_t)(row0 + r) * ldc + col], acc[m][n][r]);
        }
    }
}

// ---------------------------------------------------------------------------
// gemm_maskb: C^T = (bin(mask)[M][K] @ Bt[N][K]^T)^T. Binary A staged to LDS
// from mask bits (expansion once per element). B via global_load_lds.
// Output bf16 transposed-swizzled (ld 8192). K = 8192 (nt = 128).
// ---------------------------------------------------------------------------
template <int SWZX>
__launch_bounds__(256)
__global__ void gemm_maskb(const unsigned char* __restrict__ adjm,
                           const short* __restrict__ Bt,
                           short* __restrict__ C) {
    __shared__ short As0[128][64], Bs0[128][64];
    __shared__ short As1[128][64], Bs1[128][64];
    int bx = blockIdx.x, by = blockIdx.y;
    if (SWZX) {
        int lid = blockIdx.x + blockIdx.y * 8;
        int c = lid & 7, s = lid >> 3;
        by = c * 8 + (s >> 3);
        bx = s & 7;
    }
    const int tid  = threadIdx.x;
    const int lane = tid & 63;
    const int w    = tid >> 6;
    const int wr   = w >> 1, wc = w & 1;
    const int i0   = by * 128;
    const int n0   = bx * 128;

    const int srow = w * 32 + (lane >> 3);
    const short* gB = Bt + (size_t)(n0 + srow) * 8192 + (lane & 7) * 8;
    const int mr = tid >> 1, mh = tid & 1;
    const unsigned char* gM = adjm + (size_t)(i0 + mr) * 1024 + mh * 4;

    f32x4 acc[4][4];
    #pragma unroll
    for (int m = 0; m < 4; m++)
        #pragma unroll
        for (int n = 0; n < 4; n++) acc[m][n] = (f32x4){0.f, 0.f, 0.f, 0.f};

#define MB_BLOAD(ts, Bb)                                                        \
    do {                                                                        \
        _Pragma("unroll")                                                       \
        for (int j = 0; j < 4; j++)                                             \
            gload16(gB + (size_t)(ts) * 64 + (size_t)j * 8 * 8192,              \
                    &Bb[w * 32 + j * 8][0]);                                    \
    } while (0)

#define MB_WSTAGE(As_, mrg)                                                     \
    do {                                                                        \
        _Pragma("unroll")                                                       \
        for (int b = 0; b < 4; b++) {                                           \
            int kbr = mh * 4 + b;                                               \
            unsigned mbyte = ((mrg) >> (8 * b)) & 0xFFu;                        \
            short8 p;                                                           \
            _Pragma("unroll")                                                   \
            for (int e = 0; e < 8; e++)                                         \
                p[e] = ((mbyte >> e) & 1) ? (short)0x3F80 : (short)0;           \
            *(short8*)&As_[mr][(kbr ^ sfun(mr)) * 8] = p;                       \
        }                                                                       \
    } while (0)

    const int nt = 128;                    // K = 8192
    unsigned mreg = *(const unsigned*)(gM);
    MB_BLOAD(0, Bs0);
    for (int t = 0; t < nt; t += 2) {
        MB_WSTAGE(As0, mreg);
        __syncthreads();
        unsigned mnext = *(const unsigned*)(gM + (size_t)(t + 1) * 8);
        MB_BLOAD(t + 1, Bs1);
        MFMA_COMPUTE(As0, Bs0);
        MB_WSTAGE(As1, mnext);
        __syncthreads();
        if (t + 2 < nt) {
            mreg = *(const unsigned*)(gM + (size_t)(t + 2) * 8);
            MB_BLOAD(t + 2, Bs0);
        }
        MFMA_COMPUTE(As1, Bs1);
    }
#undef MB_BLOAD
#undef MB_WSTAGE

    // transposed-swizzled bf16 epilogue (C^T)
    #pragma unroll
    for (int m = 0; m < 4; m++) {
        #pragma unroll
        for (int n = 0; n < 4; n++) {
            int row0 = i0 + wr * 64 + m * 16 + ((lane >> 4) << 2);
            int col  = n0 + wc * 64 + n * 16 + (lane & 15);
            unsigned long long pk = 0;
            #pragma unroll
            for (int r = 0; r < 4; r++)
                pk |= (unsigned long long)(unsigned short)f2bf(acc[m][n][r])
                      << (16 * r);
            *(unsigned long long*)(C + (size_t)col * 8192 + swzk(row0, col)) = pk;
        }
    }
}

// ---------------------------------------------------------------------------
// gemm_xw_k: C[M][N]=A[M][256]@B[256][N], A,B f32. Dual-write epilogue:
// C row-major bf16 (ld=N) + Ct = C^T bf16 swizzled (ld=8192).
// ---------------------------------------------------------------------------
template <int SWZX>
__launch_bounds__(256)
__global__ void gemm_xw_k(const float* __restrict__ A, const float* __restrict__ B,
                          short* __restrict__ C, short* __restrict__ Ct, int ldn) {
    __shared__ short As[128][64];
    __shared__ short Bs[128][64];
    int bx = blockIdx.x, by = blockIdx.y;
    if (SWZX) {
        int lid = blockIdx.x + blockIdx.y * 8;
        int c = lid & 7, s = lid >> 3;
        by = c * 8 + (s >> 3);
        bx = s & 7;
    }
    const int tid  = threadIdx.x;
    const int lane = tid & 63;
    const int w    = tid >> 6;
    const int wr   = w >> 1, wc = w & 1;
    const int i0   = by * 128;
    const int n0   = bx * 128;

    f32x4 acc[4][4];
    #pragma unroll
    for (int m = 0; m < 4; m++)
        #pragma unroll
        for (int n = 0; n < 4; n++) acc[m][n] = (f32x4){0.f, 0.f, 0.f, 0.f};

    for (int ks = 0; ks < 256; ks += 64) {
        __syncthreads();
        #pragma unroll
        for (int it = 0; it < 4; it++) {
            int idx = it * 256 + tid;
            int cg = idx & 7, r = idx >> 3;
            *(short8*)&As[r][swzk(cg * 8, r)] =
                ld8<1>(A, (size_t)(i0 + r) * 256 + ks + cg * 8);
        }
        #pragma unroll
        for (int it = 0; it < 2; it++) {
            int idx = it * 256 + tid;
            int ng = idx & 15, kp = idx >> 4;
            int k = 2 * kp;
            short8 r0 = ld8<1>(B, (size_t)(ks + k) * ldn + n0 + ng * 8);
            short8 r1 = ld8<1>(B, (size_t)(ks + k + 1) * ldn + n0 + ng * 8);
            #pragma unroll
            for (int j = 0; j < 8; j++) {
                int row = ng * 8 + j;
                *(unsigned*)&Bs[row][swzk(k, row)] = pack2(r0[j], r1[j]);
            }
        }
        __syncthreads();
        MFMA_COMPUTE(As, Bs);
    }
    #pragma unroll
    for (int m = 0; m < 4; m++) {
        #pragma unroll
        for (int n = 0; n < 4; n++) {
            int row0 = i0 + wr * 64 + m * 16 + ((lane >> 4) << 2);
            int col  = n0 + wc * 64 + n * 16 + (lane & 15);
            unsigned long long pk = 0;
            #pragma unroll
            for (int r = 0; r < 4; r++) {
                short b = f2bf(acc[m][n][r]);
                C[(size_t)(row0 + r) * ldn + col] = b;
                pk |= (unsigned long long)(unsigned short)b << (16 * r);
            }
            *(unsigned long long*)(Ct + (size_t)col * 8192 + swzk(row0, col)) = pk;
        }
    }
}

// f1g[i] = h_g[i,:] . a_g[:F], f2g[i] = h_g[i,:] . a_g[F:]
__launch_bounds__(256)
__global__ void compute_f_k(const short* __restrict__ h1, const short* __restrict__ h2,
                            const float* __restrict__ ae, const float* __restrict__ aa,
                            float* __restrict__ f11, float* __restrict__ f21,
                            float* __restrict__ f12, float* __restrict__ f22) {
    int row = blockIdx.x, t = threadIdx.x;
    float s11 = 0.f, s21 = 0.f, s12 = 0.f, s22 = 0.f;
    if (t < 128) {
        float hv = bf2f(h1[(size_t)row * 128 + t]);
        s11 = hv * ae[t];
        s21 = hv * ae[128 + t];
    }
    #pragma unroll
    for (int q = 0; q < 4; q++) {
        int f = t + q * 256;
        float hv = bf2f(h2[(size_t)row * 1024 + f]);
        s12 += hv * aa[f];
        s22 += hv * aa[1024 + f];
    }
    __shared__ float red[4][4];
    s11 = wred_sum(s11); s21 = wred_sum(s21);
    s12 = wred_sum(s12); s22 = wred_sum(s22);
    int w = t >> 6;
    if ((t & 63) == 0) { red[0][w] = s11; red[1][w] = s21; red[2][w] = s12; red[3][w] = s22; }
    __syncthreads();
    if (t == 0) {
        f11[row] = red[0][0] + red[0][1] + red[0][2] + red[0][3];
        f21[row] = red[1][0] + red[1][1] + red[1][2] + red[1][3];
        f12[row] = red[2][0] + red[2][1] + red[2][2] + red[2][3];
        f22[row] = red[3][0] + red[3][1] + red[3][2] + red[3][3];
    }
}

// E/F vectors: E = exp(f), F = exp(0.2 f)
__launch_bounds__(256)
__global__ void evec_k(const float* __restrict__ f11, const float* __restrict__ f21,
                       const float* __restrict__ f12, const float* __restrict__ f22,
                       float* __restrict__ E11, float* __restrict__ F11,
                       float* __restrict__ E21, float* __restrict__ F21,
                       float* __restrict__ E12, float* __restrict__ F12,
                       float* __restrict__ E22, float* __restrict__ F22) {
    int i = blockIdx.x * 256 + threadIdx.x;
    if (i >= 8192) return;
    float a = f11[i], b = f21[i], c = f12[i], d = f22[i];
    E11[i] = __expf(a); F11[i] = __expf(0.2f * a);
    E21[i] = __expf(b); F21[i] = __expf(0.2f * b);
    E12[i] = __expf(c); F12[i] = __expf(0.2f * c);
    E22[i] = __expf(d); F22[i] = __expf(0.2f * d);
}

// One adj pass, 4 rows/block: den1/den2 + P2b (swizzled bf16) + adjm (bitmask).
__launch_bounds__(256)
__global__ void prepass_k(const float* __restrict__ adj,
                          const float* __restrict__ E11, const float* __restrict__ F11,
                          const float* __restrict__ E21, const float* __restrict__ F21,
                          const float* __restrict__ E12, const float* __restrict__ F12,
                          const float* __restrict__ E22, const float* __restrict__ F22,
                          float* __restrict__ den1, float* __restrict__ den2,
                          short* __restrict__ P2b, unsigned char* __restrict__ adjm) {
    const int r0 = blockIdx.x * 4, t = threadIdx.x;
    float e1r[4], f1r[4], e2r[4], f2r[4];
    #pragma unroll
    for (int r = 0; r < 4; r++) {
        e1r[r] = E11[r0 + r]; f1r[r] = F11[r0 + r];
        e2r[r] = E12[r0 + r]; f2r[r] = F12[r0 + r];
    }
    float d1[4] = {0.f, 0.f, 0.f, 0.f}, d2[4] = {0.f, 0.f, 0.f, 0.f};
    #pragma unroll
    for (int jc = 0; jc < 4; jc++) {
        int jb = jc * 2048 + t * 8;
        f32x4 eA0 = *(const f32x4*)(E21 + jb), eA1 = *(const f32x4*)(E21 + jb + 4);
        f32x4 fA0 = *(const f32x4*)(F21 + jb), fA1 = *(const f32x4*)(F21 + jb + 4);
        f32x4 eB0 = *(const f32x4*)(E22 + jb), eB1 = *(const f32x4*)(E22 + jb + 4);
        f32x4 fB0 = *(const f32x4*)(F22 + jb), fB1 = *(const f32x4*)(F22 + jb + 4);
        #pragma unroll
        for (int r = 0; r < 4; r++) {
            const float* ap = adj + (size_t)(r0 + r) * 8192 + jb;
            f32x4 a0 = *(const f32x4*)ap, a1 = *(const f32x4*)(ap + 4);
            short8 p2v;
            unsigned mb = 0;
            #pragma unroll
            for (int e = 0; e < 8; e++) {
                float av = e < 4 ? a0[e] : a1[e - 4];
                float eA = e < 4 ? eA0[e] : eA1[e - 4];
                float fA = e < 4 ? fA0[e] : fA1[e - 4];
                float eB = e < 4 ? eB0[e] : eB1[e - 4];
                float fB = e < 4 ? fB0[e] : fB1[e - 4];
                float x1 = fmaxf(e1r[r] * eA, f1r[r] * fA);  // exp(lrelu(f1+f2))
                float x2 = fmaxf(e2r[r] * eB, f2r[r] * fB);
                bool on = av > 0.f;
                d1[r] += on ? x1 : 0.f;
                d2[r] += on ? x2 : 0.f;
                p2v[e] = on ? f2bf(x2) : (short)0;
                mb |= (on ? 1u : 0u) << e;
            }
            *(short8*)(P2b + (size_t)(r0 + r) * 8192 + swzk(jb, r0 + r)) = p2v;
            adjm[(size_t)(r0 + r) * 1024 + (jb >> 3)] = (unsigned char)mb;
        }
    }
    __shared__ float r1s[4][4], r2s[4][4];   // [wave][row]
    #pragma unroll
    for (int r = 0; r < 4; r++) { d1[r] = wred_sum(d1[r]); d2[r] = wred_sum(d2[r]); }
    if ((t & 63) == 0) {
        #pragma unroll
        for (int r = 0; r < 4; r++) { r1s[t >> 6][r] = d1[r]; r2s[t >> 6][r] = d2[r]; }
    }
    __syncthreads();
    if (t < 4) {
        den1[r0 + t] = r1s[0][t] + r1s[1][t] + r1s[2][t] + r1s[3][t];
        den2[r0 + t] = r2s[0][t] + r2s[1][t] + r2s[2][t] + r2s[3][t];
    }
}

// zlt = transpose(elu(Y1/den1 + h1)) swizzled, fused. Block = 64 rows x 128 cols.
__launch_bounds__(256)
__global__ void epi_gat1t_k(const float* __restrict__ Y1, const float* __restrict__ den1,
                            const short* __restrict__ h1, short* __restrict__ zlt) {
    __shared__ short ts[128][65];
    int tr = blockIdx.x * 64;
    int t = threadIdx.x;
    #pragma unroll
    for (int it = 0; it < 4; it++) {
        int idx = it * 256 + t;
        int r = idx >> 4, cb = idx & 15;
        int row = tr + r;
        float d = den1[row]; d = d > 0.f ? d : 1.f;
        const float* yp = Y1 + (size_t)row * 128 + cb * 8;
        f32x4 y0 = *(const f32x4*)yp, y1 = *(const f32x4*)(yp + 4);
        short8 hv = *(const short8*)(h1 + (size_t)row * 128 + cb * 8);
        #pragma unroll
        for (int e = 0; e < 8; e++) {
            float z = (e < 4 ? y0[e] : y1[e - 4]) / d + bf2f(hv[e]);
            z = z > 0.f ? z : (__expf(z) - 1.f);
            ts[cb * 8 + e][r] = f2bf(z);
        }
    }
    __syncthreads();
    #pragma unroll
    for (int it = 0; it < 4; it++) {
        int idx = it * 256 + t;
        int c = idx >> 3, rb = idx & 7;
        short8 v = *(const short8*)&ts[c][rb * 8];
        *(short8*)(zlt + (size_t)c * 8192 + tr + ((rb ^ sfun(c)) << 3)) = v;
    }
}

// s_l row = softmax( elu(Y2/den2 + h2) ). Y2 is bf16. f32 to d_out, bf16 to ws.
__launch_bounds__(256)
__global__ void episoft_k(const short* __restrict__ Y2, const float* __restrict__ den2,
                          const short* __restrict__ h2, float* __restrict__ slo,
                          short* __restrict__ slb) {
    int row = blockIdx.x, t = threadIdx.x;
    float d = den2[row];
    d = d > 0.f ? d : 1.f;
    float inv_d = 1.f / d;
    float v[4], mx = -1e30f;
    #pragma unroll
    for (int q = 0; q < 4; q++) {
        int j = t + q * 256;
        float a = bf2f(Y2[(size_t)row * 1024 + j]) * inv_d +
                  bf2f(h2[(size_t)row * 1024 + j]);
        a = a > 0.f ? a : (__expf(a) - 1.f);
        v[q] = a;
        mx = fmaxf(mx, a);
    }
    __shared__ float sred[4];
    __shared__ float sbc;
    mx = wred_max(mx);
    if ((t & 63) == 0) sred[t >> 6] = mx;
    __syncthreads();
    if (t == 0) sbc = fmaxf(fmaxf(sred[0], sred[1]), fmaxf(sred[2], sred[3]));
    __syncthreads();
    mx = sbc;
    float s = 0.f;
    #pragma unroll
    for (int q = 0; q < 4; q++) { v[q] = __expf(v[q] - mx); s += v[q]; }
    s = wred_sum(s);
    if ((t & 63) == 0) sred[t >> 6] = s;
    __syncthreads();
    if (t == 0) sbc = sred[0] + sred[1] + sred[2] + sred[3];
    __syncthreads();
    float inv = 1.f / sbc;
    #pragma unroll
    for (int q = 0; q < 4; q++) {
        float sv = v[q] * inv;
        slo[(size_t)row * 1024 + t + q * 256] = sv;
        slb[(size_t)row * 1024 + t + q * 256] = f2bf(sv);
    }
}

// tiled transpose: in [R][C] bf16 -> out [C][R] bf16, swizzled blocks
template <int F32IN>
__launch_bounds__(256)
__global__ void transpose_swz_k(const void* __restrict__ in, short* __restrict__ out,
                                int R, int C) {
    __shared__ short ts[64][72];
    int tc = blockIdx.x * 64;
    int tr = blockIdx.y * 64;
    int t = threadIdx.x;
    #pragma unroll
    for (int h = 0; h < 2; h++) {
        int r = (t >> 3) + h * 32, c = (t & 7) * 8;
        *(short8*)&ts[r][c] = ld8<F32IN>(in, (size_t)(tr + r) * C + tc + c);
    }
    __syncthreads();
    #pragma unroll
    for (int h = 0; h < 2; h++) {
        int n = t >> 2, blk = (t & 3) + h * 4;
        short8 v;
        #pragma unroll
        for (int e = 0; e < 8; e++) v[e] = ts[blk * 8 + e][n];
        *(short8*)(out + (size_t)(tc + n) * R + tr + ((blk ^ sfun(tc + n)) << 3)) = v;
    }
}

extern "C" void kernel_launch(void* const* d_in, const int* in_sizes, int n_in,
                              void* d_out, int out_size, void* d_ws, size_t ws_size,
                              hipStream_t stream) {
    const float* x   = (const float*)d_in[0];  // [8192,256]
    const float* adj = (const float*)d_in[1];  // [8192,8192]
    const float* We  = (const float*)d_in[2];  // [256,128]
    const float* ae  = (const float*)d_in[3];  // [256]
    const float* Wa  = (const float*)d_in[4];  // [256,1024]
    const float* aa  = (const float*)d_in[5];  // [2048]
    float* out = (float*)d_out;

    char* w = (char*)d_ws;                       // 264 MiB used
    short* h1b = (short*)(w);                    // 0..2M    bf16 [8192,128]
    short* h2b = (short*)(w + (2u   << 20));     // 2..18M   bf16 [8192,1024]
    float* f11 = (float*)(w + (18u  << 20));     // 18..19M  vectors
    float* f21 = f11 + 8192;  float* f12 = f21 + 8192; float* f22 = f12 + 8192;
    float* den1 = f22 + 8192; float* den2 = den1 + 8192;
    float* E11 = den2 + 8192; float* F11 = E11 + 8192;
    float* E21 = F11 + 8192;  float* F21 = E21 + 8192;
    float* E12 = F21 + 8192;  float* F12 = E12 + 8192;
    float* E22 = F12 + 8192;  float* F22 = E22 + 8192;
    float* Y1f = (float*)(w + (21u << 20));      // 21..25M  f32  [8192,128]
    short* Y2b = (short*)(w + (25u << 20));      // 25..41M  bf16 [8192,1024]
    short* slb = (short*)(w + (57u << 20));      // 57..73M  bf16 [8192,1024]
    short* h1t = (short*)(w + (73u << 20));      // 73..75M  bf16 [128,8192]  swz
    short* h2t = (short*)(w + (75u << 20));      // 75..91M  bf16 [1024,8192] swz
    short* slt = (short*)(w + (91u << 20));      // 91..107M bf16 [1024,8192] swz
    short* zlt = (short*)(w + (107u << 20));     // 107..109M bf16 [128,8192] swz
    short* tT  = (short*)(w + (109u << 20));     // 109..125M bf16 [1024,8192] swz
    short* P2b = (short*)(w + (128u << 20));     // 128..256M bf16 [8192,8192] swz
    unsigned char* adjm = (unsigned char*)(w + (256u << 20)); // 8 MiB bitmask

    float* xo  = out;                            // xnext [1024,128]
    float* ao  = out + 131072;                   // anext [1024,1024]
    float* slo = out + 131072 + 1048576;         // s_l   [8192,1024]

    hipMemsetAsync(out, 0, (size_t)(131072 + 1048576) * 4, stream);
    hipMemsetAsync(Y1f, 0, (size_t)8192 * 128 * 4, stream);

    // h1 = x@We ; h2 = x@Wa  (dual write: row-major + transposed-swizzled)
    gemm_xw_k<0><<<dim3(1, 64), 256, 0, stream>>>(x, We, h1b, h1t, 128);
    gemm_xw_k<1><<<dim3(8, 64), 256, 0, stream>>>(x, Wa, h2b, h2t, 1024);
    compute_f_k<<<dim3(8192), 256, 0, stream>>>(h1b, h2b, ae, aa, f11, f21, f12, f22);
    evec_k<<<dim3(32), 256, 0, stream>>>(f11, f21, f12, f22,
        E11, F11, E21, F21, E12, F12, E22, F22);
    prepass_k<<<dim3(2048), 256, 0, stream>>>(adj,
        E11, F11, E21, F21, E12, F12, E22, F22, den1, den2, P2b, adjm);

    // Y1 = (mask .* w1) @ h1 (gen-GEMM, split-K x8, atomics into Y1f)
    gemm_gen<3, 0><<<dim3(1, 64, 8), 256, 0, stream>>>(
        adjm, h1t, Y1f, 128, 1024, E11, F11, E21, F21);
    epi_gat1t_k<<<dim3(128), 256, 0, stream>>>(Y1f, den1, h1b, zlt);

    // Y2 = P2 @ h2 (gload GEMM, unsplit, bf16 store)
    gemm_lds<2, 1><<<dim3(8, 64, 1), 256, 0, stream>>>(P2b, h2t, Y2b, 1024, 8192);
    episoft_k<<<dim3(8192), 256, 0, stream>>>(Y2b, den2, h2b, slo, slb);
    transpose_swz_k<0><<<dim3(16, 128), 256, 0, stream>>>(slb, slt, 8192, 1024);

    // tT = (mask @ s_l)^T  (LDS-staged binary A, fused transpose)
    gemm_maskb<1><<<dim3(8, 64), 256, 0, stream>>>(adjm, slt, tT);

    // anext = s_l^T @ t ; xnext = s_l^T @ z_l  (atomics into d_out)
    gemm_lds<3, 0><<<dim3(8, 8, 8), 256, 0, stream>>>(slt, tT, ao, 1024, 1024);
    gemm_lds<3, 0><<<dim3(1, 8, 32), 256, 0, stream>>>(slt, zlt, xo, 128, 256);
}

// Round 14
// 642.783 us; speedup vs baseline: 1.2428x; 1.0077x over previous
//
#include <hip/hip_runtime.h>
#include <hip/hip_bf16.h>

// BatchedDiffPool on MI355X. Inputs f32, outputs f32; internal bf16 MFMA.
// R13 configuration (647 us) + LDS-LUT binarize in gemm_maskb + fused evec.
//
//  h1=x@We, h2=x@Wa (dual-write) -> f-dots + E/F=exp(f),exp(0.2f) fused ->
//  prepass: den1,den2,P2b(bf16 swz),adjm(bitmask) ->
//  Y1 = (mask.*w1)@h1t (gen-GEMM, split-K x8) -> zlt = transpose(elu(Y1/den1+h1))
//  Y2 = P2b@h2t (gload GEMM, bf16 out) ->
//  s_l = softmax(elu(Y2/den2+h2)) -> d_out(f32)+slb -> slt
//  tT = (mask@slt)^T  (gemm_maskb: LUT-expanded binary A, fused transpose)
//  anext = slt@tT ; xnext = slt@zlt (split-K atomics into d_out)

#define DI __device__ __forceinline__

typedef __attribute__((ext_vector_type(8))) short short8;
typedef __attribute__((ext_vector_type(4))) float f32x4;

static DI float bf2f(short s) {
    union { unsigned u; float f; } c;
    c.u = ((unsigned)(unsigned short)s) << 16;
    return c.f;
}
static DI short f2bf(float f) {                       // RTN-even
    union { float f; unsigned u; } c; c.f = f;
    unsigned r = (c.u + 0x7FFFu + ((c.u >> 16) & 1u)) >> 16;
    return (short)(unsigned short)r;
}
// load 8 consecutive elements as bf16 shorts. F32: 0=bf16, 1=f32 RTN
template <int F32>
static DI short8 ld8(const void* base, size_t off) {
    if (F32 == 0) return *(const short8*)((const short*)base + off);
    const float* p = (const float*)base + off;
    f32x4 a = *(const f32x4*)p;
    f32x4 b = *(const f32x4*)(p + 4);
    short8 v;
    #pragma unroll
    for (int e = 0; e < 4; e++) { v[e] = f2bf(a[e]); v[4 + e] = f2bf(b[e]); }
    return v;
}
static DI float wred_sum(float v) {
    #pragma unroll
    for (int o = 32; o > 0; o >>= 1) v += __shfl_down(v, o, 64);
    return v;
}
static DI float wred_max(float v) {
    #pragma unroll
    for (int o = 32; o > 0; o >>= 1) v = fmaxf(v, __shfl_down(v, o, 64));
    return v;
}
// the ONE swizzle definition (16B blocks within each 64-short k-group)
static DI int sfun(int r) { return (r ^ (r >> 3)) & 7; }
static DI int swzk(int k, int r) {
    return (k & ~63) | ((((k >> 3) & 7) ^ sfun(r)) << 3) | (k & 7);
}
static DI unsigned pack2(short lo, short hi) {
    return ((unsigned)(unsigned short)lo) | (((unsigned)(unsigned short)hi) << 16);
}
// async global->LDS, 16B per lane; LDS dest wave-uniform base + lane*16
static DI void gload16(const void* g, void* l) {
    __builtin_amdgcn_global_load_lds(
        (const __attribute__((address_space(1))) unsigned int*)g,
        (__attribute__((address_space(3))) unsigned int*)l, 16, 0, 0);
}

// shared MFMA compute macro (all GEMMs): 2x2 waves, 4x4 fragments
#define MFMA_COMPUTE(Ab_, Bb_)                                                  \
    do {                                                                        \
        _Pragma("unroll")                                                       \
        for (int kk = 0; kk < 2; kk++) {                                        \
            short8 af[4], bq[4];                                                \
            _Pragma("unroll")                                                   \
            for (int m = 0; m < 4; m++) {                                       \
                int ar = wr * 64 + m * 16 + (lane & 15);                        \
                af[m] = *(const short8*)&Ab_[ar]                                \
                            [swzk(kk * 32 + (lane >> 4) * 8, ar)];              \
            }                                                                   \
            _Pragma("unroll")                                                   \
            for (int n = 0; n < 4; n++) {                                       \
                int br = wc * 64 + n * 16 + (lane & 15);                        \
                bq[n] = *(const short8*)&Bb_[br]                                \
                            [swzk(kk * 32 + (lane >> 4) * 8, br)];              \
            }                                                                   \
            _Pragma("unroll")                                                   \
            for (int m = 0; m < 4; m++)                                         \
                _Pragma("unroll")                                               \
                for (int n = 0; n < 4; n++)                                     \
                    acc[m][n] = __builtin_amdgcn_mfma_f32_16x16x32_bf16(        \
                        af[m], bq[n], acc[m][n], 0, 0, 0);                      \
        }                                                                       \
    } while (0)

// ---------------------------------------------------------------------------
// gemm_lds: C = A[M][K] * Bt[N][K]^T, A/Bt bf16 row-major PRE-SWIZZLED,
// lda = ldbt = 8192. 2-phase double-buffered global_load_lds staging.
// EPI: 0 = f32 store, 2 = bf16 row-major store, 3 = f32 atomicAdd.
// kcount/64 EVEN. grid z = k-split.
// ---------------------------------------------------------------------------
template <int EPI, int SWZX>
__launch_bounds__(256)
__global__ void gemm_lds(const short* __restrict__ A, const short* __restrict__ Bt,
                         void* __restrict__ C, int ldc, int kcount) {
    __shared__ short As0[128][64], Bs0[128][64];
    __shared__ short As1[128][64], Bs1[128][64];
    int bx = blockIdx.x, by = blockIdx.y;
    if (SWZX) {
        int lid = blockIdx.x + blockIdx.y * 8;
        int c = lid & 7, s = lid >> 3;
        by = c * 8 + (s >> 3);
        bx = s & 7;
    }
    const int tid  = threadIdx.x;
    const int lane = tid & 63;
    const int w    = tid >> 6;
    const int wr   = w >> 1, wc = w & 1;
    const int i0   = by * 128;
    const int n0   = bx * 128;
    const int k0   = blockIdx.z * kcount;

    const int srow = w * 32 + (lane >> 3);
    const short* gA = A  + (size_t)(i0 + srow) * 8192 + k0 + (lane & 7) * 8;
    const short* gB = Bt + (size_t)(n0 + srow) * 8192 + k0 + (lane & 7) * 8;

    f32x4 acc[4][4];
    #pragma unroll
    for (int m = 0; m < 4; m++)
        #pragma unroll
        for (int n = 0; n < 4; n++) acc[m][n] = (f32x4){0.f, 0.f, 0.f, 0.f};

#define STAGE_TILE(ts, Ab, Bb)                                                  \
    do {                                                                        \
        _Pragma("unroll")                                                       \
        for (int j = 0; j < 4; j++) {                                           \
            gload16(gA + (size_t)(ts) * 64 + (size_t)j * 8 * 8192,              \
                    &Ab[w * 32 + j * 8][0]);                                    \
            gload16(gB + (size_t)(ts) * 64 + (size_t)j * 8 * 8192,              \
                    &Bb[w * 32 + j * 8][0]);                                    \
        }                                                                       \
    } while (0)

    const int nt = kcount >> 6;            // even at every call site
    STAGE_TILE(0, As0, Bs0);
    for (int t = 0; t < nt; t += 2) {
        __syncthreads();
        STAGE_TILE(t + 1, As1, Bs1);
        MFMA_COMPUTE(As0, Bs0);
        __syncthreads();
        if (t + 2 < nt) STAGE_TILE(t + 2, As0, Bs0);
        MFMA_COMPUTE(As1, Bs1);
    }
#undef STAGE_TILE

    #pragma unroll
    for (int m = 0; m < 4; m++) {
        #pragma unroll
        for (int n = 0; n < 4; n++) {
            int row0 = i0 + wr * 64 + m * 16 + ((lane >> 4) << 2);
            int col  = n0 + wc * 64 + n * 16 + (lane & 15);
            #pragma unroll
            for (int r = 0; r < 4; r++) {
                float v = acc[m][n][r];
                if (EPI == 0)      ((float*)C)[(size_t)(row0 + r) * ldc + col] = v;
                else if (EPI == 2) ((short*)C)[(size_t)(row0 + r) * ldc + col] = f2bf(v);
                else atomicAdd(&((float*)C)[(size_t)(row0 + r) * ldc + col], v);
            }
        }
    }
}

// ---------------------------------------------------------------------------
// gemm_gen: C = gen(mask)[M][K] * Bt[N][K]^T with
// a_ik = bit_ik * max(E1[i]E2[k], F1[i]F2[k]). Mask bits from adjm; A staged
// to LDS swizzled. B via global_load_lds. EPI=3 atomicAdd. kcount/64 EVEN.
// (Use ONLY where the A-panel is consumed by ONE n-block — R12 lesson.)
// ---------------------------------------------------------------------------
template <int EPI, int SWZX>
__launch_bounds__(256)
__global__ void gemm_gen(const unsigned char* __restrict__ adjm,
                         const short* __restrict__ Bt,
                         float* __restrict__ C, int ldc, int kcount,
                         const float* __restrict__ E1, const float* __restrict__ F1,
                         const float* __restrict__ E2, const float* __restrict__ F2) {
    __shared__ short As0[128][64], Bs0[128][64];
    __shared__ short As1[128][64], Bs1[128][64];
    int bx = blockIdx.x, by = blockIdx.y;
    if (SWZX) {
        int lid = blockIdx.x + blockIdx.y * 8;
        int c = lid & 7, s = lid >> 3;
        by = c * 8 + (s >> 3);
        bx = s & 7;
    }
    const int tid  = threadIdx.x;
    const int lane = tid & 63;
    const int w    = tid >> 6;
    const int wr   = w >> 1, wc = w & 1;
    const int i0   = by * 128;
    const int n0   = bx * 128;
    const int k0   = blockIdx.z * kcount;

    const int srow = w * 32 + (lane >> 3);
    const short* gB = Bt + (size_t)(n0 + srow) * 8192 + k0 + (lane & 7) * 8;
    const int mr = tid >> 1, mh = tid & 1;        // staging row / k-half
    const unsigned char* gM = adjm + (size_t)(i0 + mr) * 1024 + (k0 >> 3) + mh * 4;
    const float e1v = E1[i0 + mr], f1v = F1[i0 + mr];

    f32x4 acc[4][4];
    #pragma unroll
    for (int m = 0; m < 4; m++)
        #pragma unroll
        for (int n = 0; n < 4; n++) acc[m][n] = (f32x4){0.f, 0.f, 0.f, 0.f};

    unsigned mreg;   // 32 mask bits for (mr, k-half)

#define G_ALOAD(ts)                                                             \
    do { mreg = *(const unsigned*)(gM + (size_t)(ts) * 8); } while (0)

#define G_BLOAD(ts, Bb)                                                         \
    do {                                                                        \
        _Pragma("unroll")                                                       \
        for (int j = 0; j < 4; j++)                                             \
            gload16(gB + (size_t)(ts) * 64 + (size_t)j * 8 * 8192,              \
                    &Bb[w * 32 + j * 8][0]);                                    \
    } while (0)

#define G_WSTAGE(ts, As_)                                                       \
    do {                                                                        \
        _Pragma("unroll")                                                       \
        for (int b = 0; b < 4; b++) {                                           \
            int kbr = mh * 4 + b;                                               \
            int rk = k0 + (ts) * 64 + kbr * 8;                                  \
            unsigned mbyte = (mreg >> (8 * b)) & 0xFFu;                         \
            f32x4 e2a = *(const f32x4*)(E2 + rk);                               \
            f32x4 e2b = *(const f32x4*)(E2 + rk + 4);                           \
            f32x4 f2a = *(const f32x4*)(F2 + rk);                               \
            f32x4 f2b = *(const f32x4*)(F2 + rk + 4);                           \
            short8 p;                                                           \
            _Pragma("unroll")                                                   \
            for (int e = 0; e < 8; e++) {                                       \
                float ev = e < 4 ? e2a[e] : e2b[e - 4];                         \
                float fv = e < 4 ? f2a[e] : f2b[e - 4];                         \
                float wg = fmaxf(e1v * ev, f1v * fv);                           \
                p[e] = ((mbyte >> e) & 1) ? f2bf(wg) : (short)0;                \
            }                                                                   \
            *(short8*)&As_[mr][(kbr ^ sfun(mr)) * 8] = p;                       \
        }                                                                       \
    } while (0)

    const int nt = kcount >> 6;            // even
    G_ALOAD(0);
    G_BLOAD(0, Bs0);
    for (int t = 0; t < nt; t += 2) {
        G_WSTAGE(t, As0);
        __syncthreads();
        G_ALOAD(t + 1);
        G_BLOAD(t + 1, Bs1);
        MFMA_COMPUTE(As0, Bs0);
        G_WSTAGE(t + 1, As1);
        __syncthreads();
        if (t + 2 < nt) { G_ALOAD(t + 2); G_BLOAD(t + 2, Bs0); }
        MFMA_COMPUTE(As1, Bs1);
    }
#undef G_ALOAD
#undef G_BLOAD
#undef G_WSTAGE

    #pragma unroll
    for (int m = 0; m < 4; m++) {
        #pragma unroll
        for (int n = 0; n < 4; n++) {
            int row0 = i0 + wr * 64 + m * 16 + ((lane >> 4) << 2);
            int col  = n0 + wc * 64 + n * 16 + (lane & 15);
            #pragma unroll
            for (int r = 0; r < 4; r++)
                atomicAdd(&C[(size_t)(row0 + r) * ldc + col], acc[m][n][r]);
        }
    }
}

// ---------------------------------------------------------------------------
// gemm_maskb: C^T = (bin(mask)[M][K] @ Bt[N][K]^T)^T. Binary A expanded via a
// 4 KB LDS LUT (byte -> 8 bf16; ds_read_b128 + ds_write_b128 per 8 elems,
// replacing ~16 VALU ops). B via global_load_lds. Output bf16
// transposed-swizzled (ld 8192). K = 8192 (nt = 128).
// ---------------------------------------------------------------------------
template <int SWZX>
__launch_bounds__(256)
__global__ void gemm_maskb(const unsigned char* __restrict__ adjm,
                           const short* __restrict__ Bt,
                           short* __restrict__ C) {
    __shared__ short As0[128][64], Bs0[128][64];
    __shared__ short As1[128][64], Bs1[128][64];
    __shared__ __align__(16) short lutb[256][8];   // byte -> 8 bf16 (0 / 1.0)
    int bx = blockIdx.x, by = blockIdx.y;
    if (SWZX) {
        int lid = blockIdx.x + blockIdx.y * 8;
        int c = lid & 7, s = lid >> 3;
        by = c * 8 + (s >> 3);
        bx = s & 7;
    }
    const int tid  = threadIdx.x;
    const int lane = tid & 63;
    const int w    = tid >> 6;
    const int wr   = w >> 1, wc = w & 1;
    const int i0   = by * 128;
    const int n0   = bx * 128;

    const int srow = w * 32 + (lane >> 3);
    const short* gB = Bt + (size_t)(n0 + srow) * 8192 + (lane & 7) * 8;
    const int mr = tid >> 1, mh = tid & 1;
    const unsigned char* gM = adjm + (size_t)(i0 + mr) * 1024 + mh * 4;

    // build LUT (each thread fills its own 16B entry)
    {
        short8 ent;
        #pragma unroll
        for (int e = 0; e < 8; e++)
            ent[e] = ((tid >> e) & 1) ? (short)0x3F80 : (short)0;
        *(short8*)&lutb[tid][0] = ent;
    }

    f32x4 acc[4][4];
    #pragma unroll
    for (int m = 0; m < 4; m++)
        #pragma unroll
        for (int n = 0; n < 4; n++) acc[m][n] = (f32x4){0.f, 0.f, 0.f, 0.f};

#define MB_BLOAD(ts, Bb)                                                        \
    do {                                                                        \
        _Pragma("unroll")                                                       \
        for (int j = 0; j < 4; j++)                                             \
            gload16(gB + (size_t)(ts) * 64 + (size_t)j * 8 * 8192,              \
                    &Bb[w * 32 + j * 8][0]);                                    \
    } while (0)

#define MB_WSTAGE(As_, mrg)                                                     \
    do {                                                                        \
        _Pragma("unroll")                                                       \
        for (int b = 0; b < 4; b++) {                                           \
            int kbr = mh * 4 + b;                                               \
            unsigned mbyte = ((mrg) >> (8 * b)) & 0xFFu;                        \
            short8 p = *(const short8*)&lutb[mbyte][0];                         \
            *(short8*)&As_[mr][(kbr ^ sfun(mr)) * 8] = p;                       \
        }                                                                       \
    } while (0)

    const int nt = 128;                    // K = 8192
    unsigned mreg = *(const unsigned*)(gM);
    MB_BLOAD(0, Bs0);
    __syncthreads();                       // LUT visible to all waves
    for (int t = 0; t < nt; t += 2) {
        MB_WSTAGE(As0, mreg);
        __syncthreads();
        unsigned mnext = *(const unsigned*)(gM + (size_t)(t + 1) * 8);
        MB_BLOAD(t + 1, Bs1);
        MFMA_COMPUTE(As0, Bs0);
        MB_WSTAGE(As1, mnext);
        __syncthreads();
        if (t + 2 < nt) {
            mreg = *(const unsigned*)(gM + (size_t)(t + 2) * 8);
            MB_BLOAD(t + 2, Bs0);
        }
        MFMA_COMPUTE(As1, Bs1);
    }
#undef MB_BLOAD
#undef MB_WSTAGE

    // transposed-swizzled bf16 epilogue (C^T)
    #pragma unroll
    for (int m = 0; m < 4; m++) {
        #pragma unroll
        for (int n = 0; n < 4; n++) {
            int row0 = i0 + wr * 64 + m * 16 + ((lane >> 4) << 2);
            int col  = n0 + wc * 64 + n * 16 + (lane & 15);
            unsigned long long pk = 0;
            #pragma unroll
            for (int r = 0; r < 4; r++)
                pk |= (unsigned long long)(unsigned short)f2bf(acc[m][n][r])
                      << (16 * r);
            *(unsigned long long*)(C + (size_t)col * 8192 + swzk(row0, col)) = pk;
        }
    }
}

// ---------------------------------------------------------------------------
// gemm_xw_k: C[M][N]=A[M][256]@B[256][N], A,B f32. Dual-write epilogue:
// C row-major bf16 (ld=N) + Ct = C^T bf16 swizzled (ld=8192).
// ---------------------------------------------------------------------------
template <int SWZX>
__launch_bounds__(256)
__global__ void gemm_xw_k(const float* __restrict__ A, const float* __restrict__ B,
                          short* __restrict__ C, short* __restrict__ Ct, int ldn) {
    __shared__ short As[128][64];
    __shared__ short Bs[128][64];
    int bx = blockIdx.x, by = blockIdx.y;
    if (SWZX) {
        int lid = blockIdx.x + blockIdx.y * 8;
        int c = lid & 7, s = lid >> 3;
        by = c * 8 + (s >> 3);
        bx = s & 7;
    }
    const int tid  = threadIdx.x;
    const int lane = tid & 63;
    const int w    = tid >> 6;
    const int wr   = w >> 1, wc = w & 1;
    const int i0   = by * 128;
    const int n0   = bx * 128;

    f32x4 acc[4][4];
    #pragma unroll
    for (int m = 0; m < 4; m++)
        #pragma unroll
        for (int n = 0; n < 4; n++) acc[m][n] = (f32x4){0.f, 0.f, 0.f, 0.f};

    for (int ks = 0; ks < 256; ks += 64) {
        __syncthreads();
        #pragma unroll
        for (int it = 0; it < 4; it++) {
            int idx = it * 256 + tid;
            int cg = idx & 7, r = idx >> 3;
            *(short8*)&As[r][swzk(cg * 8, r)] =
                ld8<1>(A, (size_t)(i0 + r) * 256 + ks + cg * 8);
        }
        #pragma unroll
        for (int it = 0; it < 2; it++) {
            int idx = it * 256 + tid;
            int ng = idx & 15, kp = idx >> 4;
            int k = 2 * kp;
            short8 r0 = ld8<1>(B, (size_t)(ks + k) * ldn + n0 + ng * 8);
            short8 r1 = ld8<1>(B, (size_t)(ks + k + 1) * ldn + n0 + ng * 8);
            #pragma unroll
            for (int j = 0; j < 8; j++) {
                int row = ng * 8 + j;
                *(unsigned*)&Bs[row][swzk(k, row)] = pack2(r0[j], r1[j]);
            }
        }
        __syncthreads();
        MFMA_COMPUTE(As, Bs);
    }
    #pragma unroll
    for (int m = 0; m < 4; m++) {
        #pragma unroll
        for (int n = 0; n < 4; n++) {
            int row0 = i0 + wr * 64 + m * 16 + ((lane >> 4) << 2);
            int col  = n0 + wc * 64 + n * 16 + (lane & 15);
            unsigned long long pk = 0;
            #pragma unroll
            for (int r = 0; r < 4; r++) {
                short b = f2bf(acc[m][n][r]);
                C[(size_t)(row0 + r) * ldn + col] = b;
                pk |= (unsigned long long)(unsigned short)b << (16 * r);
            }
            *(unsigned long long*)(Ct + (size_t)col * 8192 + swzk(row0, col)) = pk;
        }
    }
}

// f-dots + E/F vectors fused: per row, f = h.a dots; E = exp(f), F = exp(0.2f)
__launch_bounds__(256)
__global__ void compute_f_k(const short* __restrict__ h1, const short* __restrict__ h2,
                            const float* __restrict__ ae, const float* __restrict__ aa,
                            float* __restrict__ E11, float* __restrict__ F11,
                            float* __restrict__ E21, float* __restrict__ F21,
                            float* __restrict__ E12, float* __restrict__ F12,
                            float* __restrict__ E22, float* __restrict__ F22) {
    int row = blockIdx.x, t = threadIdx.x;
    float s11 = 0.f, s21 = 0.f, s12 = 0.f, s22 = 0.f;
    if (t < 128) {
        float hv = bf2f(h1[(size_t)row * 128 + t]);
        s11 = hv * ae[t];
        s21 = hv * ae[128 + t];
    }
    #pragma unroll
    for (int q = 0; q < 4; q++) {
        int f = t + q * 256;
        float hv = bf2f(h2[(size_t)row * 1024 + f]);
        s12 += hv * aa[f];
        s22 += hv * aa[1024 + f];
    }
    __shared__ float red[4][4];
    s11 = wred_sum(s11); s21 = wred_sum(s21);
    s12 = wred_sum(s12); s22 = wred_sum(s22);
    int w = t >> 6;
    if ((t & 63) == 0) { red[0][w] = s11; red[1][w] = s21; red[2][w] = s12; red[3][w] = s22; }
    __syncthreads();
    if (t == 0) {
        float a = red[0][0] + red[0][1] + red[0][2] + red[0][3];
        float b = red[1][0] + red[1][1] + red[1][2] + red[1][3];
        float c = red[2][0] + red[2][1] + red[2][2] + red[2][3];
        float d = red[3][0] + red[3][1] + red[3][2] + red[3][3];
        E11[row] = __expf(a); F11[row] = __expf(0.2f * a);
        E21[row] = __expf(b); F21[row] = __expf(0.2f * b);
        E12[row] = __expf(c); F12[row] = __expf(0.2f * c);
        E22[row] = __expf(d); F22[row] = __expf(0.2f * d);
    }
}

// One adj pass, 4 rows/block: den1/den2 + P2b (swizzled bf16) + adjm (bitmask).
__launch_bounds__(256)
__global__ void prepass_k(const float* __restrict__ adj,
                          const float* __restrict__ E11, const float* __restrict__ F11,
                          const float* __restrict__ E21, const float* __restrict__ F21,
                          const float* __restrict__ E12, const float* __restrict__ F12,
                          const float* __restrict__ E22, const float* __restrict__ F22,
                          float* __restrict__ den1, float* __restrict__ den2,
                          short* __restrict__ P2b, unsigned char* __restrict__ adjm) {
    const int r0 = blockIdx.x * 4, t = threadIdx.x;
    float e1r[4], f1r[4], e2r[4], f2r[4];
    #pragma unroll
    for (int r = 0; r < 4; r++) {
        e1r[r] = E11[r0 + r]; f1r[r] = F11[r0 + r];
        e2r[r] = E12[r0 + r]; f2r[r] = F12[r0 + r];
    }
    float d1[4] = {0.f, 0.f, 0.f, 0.f}, d2[4] = {0.f, 0.f, 0.f, 0.f};
    #pragma unroll
    for (int jc = 0; jc < 4; jc++) {
        int jb = jc * 2048 + t * 8;
        f32x4 eA0 = *(const f32x4*)(E21 + jb), eA1 = *(const f32x4*)(E21 + jb + 4);
        f32x4 fA0 = *(const f32x4*)(F21 + jb), fA1 = *(const f32x4*)(F21 + jb + 4);
        f32x4 eB0 = *(const f32x4*)(E22 + jb), eB1 = *(const f32x4*)(E22 + jb + 4);
        f32x4 fB0 = *(const f32x4*)(F22 + jb), fB1 = *(const f32x4*)(F22 + jb + 4);
        #pragma unroll
        for (int r = 0; r < 4; r++) {
            const float* ap = adj + (size_t)(r0 + r) * 8192 + jb;
            f32x4 a0 = *(const f32x4*)ap, a1 = *(const f32x4*)(ap + 4);
            short8 p2v;
            unsigned mb = 0;
            #pragma unroll
            for (int e = 0; e < 8; e++) {
                float av = e < 4 ? a0[e] : a1[e - 4];
                float eA = e < 4 ? eA0[e] : eA1[e - 4];
                float fA = e < 4 ? fA0[e] : fA1[e - 4];
                float eB = e < 4 ? eB0[e] : eB1[e - 4];
                float fB = e < 4 ? fB0[e] : fB1[e - 4];
                float x1 = fmaxf(e1r[r] * eA, f1r[r] * fA);  // exp(lrelu(f1+f2))
                float x2 = fmaxf(e2r[r] * eB, f2r[r] * fB);
                bool on = av > 0.f;
                d1[r] += on ? x1 : 0.f;
                d2[r] += on ? x2 : 0.f;
                p2v[e] = on ? f2bf(x2) : (short)0;
                mb |= (on ? 1u : 0u) << e;
            }
            *(short8*)(P2b + (size_t)(r0 + r) * 8192 + swzk(jb, r0 + r)) = p2v;
            adjm[(size_t)(r0 + r) * 1024 + (jb >> 3)] = (unsigned char)mb;
        }
    }
    __shared__ float r1s[4][4], r2s[4][4];   // [wave][row]
    #pragma unroll
    for (int r = 0; r < 4; r++) { d1[r] = wred_sum(d1[r]); d2[r] = wred_sum(d2[r]); }
    if ((t & 63) == 0) {
        #pragma unroll
        for (int r = 0; r < 4; r++) { r1s[t >> 6][r] = d1[r]; r2s[t >> 6][r] = d2[r]; }
    }
    __syncthreads();
    if (t < 4) {
        den1[r0 + t] = r1s[0][t] + r1s[1][t] + r1s[2][t] + r1s[3][t];
        den2[r0 + t] = r2s[0][t] + r2s[1][t] + r2s[2][t] + r2s[3][t];
    }
}

// zlt = transpose(elu(Y1/den1 + h1)) swizzled, fused. Block = 64 rows x 128 cols.
__launch_bounds__(256)
__global__ void epi_gat1t_k(const float* __restrict__ Y1, const float* __restrict__ den1,
                            const short* __restrict__ h1, short* __restrict__ zlt) {
    __shared__ short ts[128][65];
    int tr = blockIdx.x * 64;
    int t = threadIdx.x;
    #pragma unroll
    for (int it = 0; it < 4; it++) {
        int idx = it * 256 + t;
        int r = idx >> 4, cb = idx & 15;
        int row = tr + r;
        float d = den1[row]; d = d > 0.f ? d : 1.f;
        const float* yp = Y1 + (size_t)row * 128 + cb * 8;
        f32x4 y0 = *(const f32x4*)yp, y1 = *(const f32x4*)(yp + 4);
        short8 hv = *(const short8*)(h1 + (size_t)row * 128 + cb * 8);
        #pragma unroll
        for (int e = 0; e < 8; e++) {
            float z = (e < 4 ? y0[e] : y1[e - 4]) / d + bf2f(hv[e]);
            z = z > 0.f ? z : (__expf(z) - 1.f);
            ts[cb * 8 + e][r] = f2bf(z);
        }
    }
    __syncthreads();
    #pragma unroll
    for (int it = 0; it < 4; it++) {
        int idx = it * 256 + t;
        int c = idx >> 3, rb = idx & 7;
        short8 v = *(const short8*)&ts[c][rb * 8];
        *(short8*)(zlt + (size_t)c * 8192 + tr + ((rb ^ sfun(c)) << 3)) = v;
    }
}

// s_l row = softmax( elu(Y2/den2 + h2) ). Y2 is bf16. f32 to d_out, bf16 to ws.
__launch_bounds__(256)
__global__ void episoft_k(const short* __restrict__ Y2, const float* __restrict__ den2,
                          const short* __restrict__ h2, float* __restrict__ slo,
                          short* __restrict__ slb) {
    int row = blockIdx.x, t = threadIdx.x;
    float d = den2[row];
    d = d > 0.f ? d : 1.f;
    float inv_d = 1.f / d;
    float v[4], mx = -1e30f;
    #pragma unroll
    for (int q = 0; q < 4; q++) {
        int j = t + q * 256;
        float a = bf2f(Y2[(size_t)row * 1024 + j]) * inv_d +
                  bf2f(h2[(size_t)row * 1024 + j]);
        a = a > 0.f ? a : (__expf(a) - 1.f);
        v[q] = a;
        mx = fmaxf(mx, a);
    }
    __shared__ float sred[4];
    __shared__ float sbc;
    mx = wred_max(mx);
    if ((t & 63) == 0) sred[t >> 6] = mx;
    __syncthreads();
    if (t == 0) sbc = fmaxf(fmaxf(sred[0], sred[1]), fmaxf(sred[2], sred[3]));
    __syncthreads();
    mx = sbc;
    float s = 0.f;
    #pragma unroll
    for (int q = 0; q < 4; q++) { v[q] = __expf(v[q] - mx); s += v[q]; }
    s = wred_sum(s);
    if ((t & 63) == 0) sred[t >> 6] = s;
    __syncthreads();
    if (t == 0) sbc = sred[0] + sred[1] + sred[2] + sred[3];
    __syncthreads();
    float inv = 1.f / sbc;
    #pragma unroll
    for (int q = 0; q < 4; q++) {
        float sv = v[q] * inv;
        slo[(size_t)row * 1024 + t + q * 256] = sv;
        slb[(size_t)row * 1024 + t + q * 256] = f2bf(sv);
    }
}

// tiled transpose: in [R][C] bf16 -> out [C][R] bf16, swizzled blocks
template <int F32IN>
__launch_bounds__(256)
__global__ void transpose_swz_k(const void* __restrict__ in, short* __restrict__ out,
                                int R, int C) {
    __shared__ short ts[64][72];
    int tc = blockIdx.x * 64;
    int tr = blockIdx.y * 64;
    int t = threadIdx.x;
    #pragma unroll
    for (int h = 0; h < 2; h++) {
        int r = (t >> 3) + h * 32, c = (t & 7) * 8;
        *(short8*)&ts[r][c] = ld8<F32IN>(in, (size_t)(tr + r) * C + tc + c);
    }
    __syncthreads();
    #pragma unroll
    for (int h = 0; h < 2; h++) {
        int n = t >> 2, blk = (t & 3) + h * 4;
        short8 v;
        #pragma unroll
        for (int e = 0; e < 8; e++) v[e] = ts[blk * 8 + e][n];
        *(short8*)(out + (size_t)(tc + n) * R + tr + ((blk ^ sfun(tc + n)) << 3)) = v;
    }
}

extern "C" void kernel_launch(void* const* d_in, const int* in_sizes, int n_in,
                              void* d_out, int out_size, void* d_ws, size_t ws_size,
                              hipStream_t stream) {
    const float* x   = (const float*)d_in[0];  // [8192,256]
    const float* adj = (const float*)d_in[1];  // [8192,8192]
    const float* We  = (const float*)d_in[2];  // [256,128]
    const float* ae  = (const float*)d_in[3];  // [256]
    const float* Wa  = (const float*)d_in[4];  // [256,1024]
    const float* aa  = (const float*)d_in[5];  // [2048]
    float* out = (float*)d_out;

    char* w = (char*)d_ws;                       // 264 MiB used
    short* h1b = (short*)(w);                    // 0..2M    bf16 [8192,128]
    short* h2b = (short*)(w + (2u   << 20));     // 2..18M   bf16 [8192,1024]
    float* E11 = (float*)(w + (18u  << 20));     // 18..19M  vectors
    float* F11 = E11 + 8192;  float* E21 = F11 + 8192; float* F21 = E21 + 8192;
    float* E12 = F21 + 8192;  float* F12 = E12 + 8192;
    float* E22 = F12 + 8192;  float* F22 = E22 + 8192;
    float* den1 = F22 + 8192; float* den2 = den1 + 8192;
    float* Y1f = (float*)(w + (21u << 20));      // 21..25M  f32  [8192,128]
    short* Y2b = (short*)(w + (25u << 20));      // 25..41M  bf16 [8192,1024]
    short* slb = (short*)(w + (57u << 20));      // 57..73M  bf16 [8192,1024]
    short* h1t = (short*)(w + (73u << 20));      // 73..75M  bf16 [128,8192]  swz
    short* h2t = (short*)(w + (75u << 20));      // 75..91M  bf16 [1024,8192] swz
    short* slt = (short*)(w + (91u << 20));      // 91..107M bf16 [1024,8192] swz
    short* zlt = (short*)(w + (107u << 20));     // 107..109M bf16 [128,8192] swz
    short* tT  = (short*)(w + (109u << 20));     // 109..125M bf16 [1024,8192] swz
    short* P2b = (short*)(w + (128u << 20));     // 128..256M bf16 [8192,8192] swz
    unsigned char* adjm = (unsigned char*)(w + (256u << 20)); // 8 MiB bitmask

    float* xo  = out;                            // xnext [1024,128]
    float* ao  = out + 131072;                   // anext [1024,1024]
    float* slo = out + 131072 + 1048576;         // s_l   [8192,1024]

    hipMemsetAsync(out, 0, (size_t)(131072 + 1048576) * 4, stream);
    hipMemsetAsync(Y1f, 0, (size_t)8192 * 128 * 4, stream);

    // h1 = x@We ; h2 = x@Wa  (dual write: row-major + transposed-swizzled)
    gemm_xw_k<0><<<dim3(1, 64), 256, 0, stream>>>(x, We, h1b, h1t, 128);
    gemm_xw_k<1><<<dim3(8, 64), 256, 0, stream>>>(x, Wa, h2b, h2t, 1024);
    compute_f_k<<<dim3(8192), 256, 0, stream>>>(h1b, h2b, ae, aa,
        E11, F11, E21, F21, E12, F12, E22, F22);
    prepass_k<<<dim3(2048), 256, 0, stream>>>(adj,
        E11, F11, E21, F21, E12, F12, E22, F22, den1, den2, P2b, adjm);

    // Y1 = (mask .* w1) @ h1 (gen-GEMM, split-K x8, atomics into Y1f)
    gemm_gen<3, 0><<<dim3(1, 64, 8), 256, 0, stream>>>(
        adjm, h1t, Y1f, 128, 1024, E11, F11, E21, F21);
    epi_gat1t_k<<<dim3(128), 256, 0, stream>>>(Y1f, den1, h1b, zlt);

    // Y2 = P2 @ h2 (gload GEMM, unsplit, bf16 store)
    gemm_lds<2, 1><<<dim3(8, 64, 1), 256, 0, stream>>>(P2b, h2t, Y2b, 1024, 8192);
    episoft_k<<<dim3(8192), 256, 0, stream>>>(Y2b, den2, h2b, slo, slb);
    transpose_swz_k<0><<<dim3(16, 128), 256, 0, stream>>>(slb, slt, 8192, 1024);

    // tT = (mask @ s_l)^T  (LUT-expanded binary A, fused transpose)
    gemm_maskb<1><<<dim3(8, 64), 256, 0, stream>>>(adjm, slt, tT);

    // anext = s_l^T @ t ; xnext = s_l^T @ z_l  (atomics into d_out)
    gemm_lds<3, 0><<<dim3(8, 8, 8), 256, 0, stream>>>(slt, tT, ao, 1024, 1024);
    gemm_lds<3, 0><<<dim3(1, 8, 32), 256, 0, stream>>>(slt, zlt, xo, 128, 256);
}

// Round 15
// 637.622 us; speedup vs baseline: 1.2528x; 1.0081x over previous
//
#include <hip/hip_runtime.h>
#include <hip/hip_bf16.h>

// BatchedDiffPool on MI355X. Inputs f32, outputs f32; internal bf16 MFMA.
// R14 configuration (642 us) + 8-row prepass (E/F loads amortized 8x).
//
//  h1=x@We, h2=x@Wa (dual-write) -> f-dots + E/F=exp(f),exp(0.2f) fused ->
//  prepass: den1,den2,P2b(bf16 swz),adjm(bitmask) ->
//  Y1 = (mask.*w1)@h1t (gen-GEMM, split-K x8) -> zlt = transpose(elu(Y1/den1+h1))
//  Y2 = P2b@h2t (gload GEMM, bf16 out) ->
//  s_l = softmax(elu(Y2/den2+h2)) -> d_out(f32)+slb -> slt
//  tT = (mask@slt)^T  (gemm_maskb: LUT-expanded binary A, fused transpose)
//  anext = slt@tT ; xnext = slt@zlt (split-K atomics into d_out)

#define DI __device__ __forceinline__

typedef __attribute__((ext_vector_type(8))) short short8;
typedef __attribute__((ext_vector_type(4))) float f32x4;

static DI float bf2f(short s) {
    union { unsigned u; float f; } c;
    c.u = ((unsigned)(unsigned short)s) << 16;
    return c.f;
}
static DI short f2bf(float f) {                       // RTN-even
    union { float f; unsigned u; } c; c.f = f;
    unsigned r = (c.u + 0x7FFFu + ((c.u >> 16) & 1u)) >> 16;
    return (short)(unsigned short)r;
}
// load 8 consecutive elements as bf16 shorts. F32: 0=bf16, 1=f32 RTN
template <int F32>
static DI short8 ld8(const void* base, size_t off) {
    if (F32 == 0) return *(const short8*)((const short*)base + off);
    const float* p = (const float*)base + off;
    f32x4 a = *(const f32x4*)p;
    f32x4 b = *(const f32x4*)(p + 4);
    short8 v;
    #pragma unroll
    for (int e = 0; e < 4; e++) { v[e] = f2bf(a[e]); v[4 + e] = f2bf(b[e]); }
    return v;
}
static DI float wred_sum(float v) {
    #pragma unroll
    for (int o = 32; o > 0; o >>= 1) v += __shfl_down(v, o, 64);
    return v;
}
static DI float wred_max(float v) {
    #pragma unroll
    for (int o = 32; o > 0; o >>= 1) v = fmaxf(v, __shfl_down(v, o, 64));
    return v;
}
// the ONE swizzle definition (16B blocks within each 64-short k-group)
static DI int sfun(int r) { return (r ^ (r >> 3)) & 7; }
static DI int swzk(int k, int r) {
    return (k & ~63) | ((((k >> 3) & 7) ^ sfun(r)) << 3) | (k & 7);
}
static DI unsigned pack2(short lo, short hi) {
    return ((unsigned)(unsigned short)lo) | (((unsigned)(unsigned short)hi) << 16);
}
// async global->LDS, 16B per lane; LDS dest wave-uniform base + lane*16
static DI void gload16(const void* g, void* l) {
    __builtin_amdgcn_global_load_lds(
        (const __attribute__((address_space(1))) unsigned int*)g,
        (__attribute__((address_space(3))) unsigned int*)l, 16, 0, 0);
}

// shared MFMA compute macro (all GEMMs): 2x2 waves, 4x4 fragments
#define MFMA_COMPUTE(Ab_, Bb_)                                                  \
    do {                                                                        \
        _Pragma("unroll")                                                       \
        for (int kk = 0; kk < 2; kk++) {                                        \
            short8 af[4], bq[4];                                                \
            _Pragma("unroll")                                                   \
            for (int m = 0; m < 4; m++) {                                       \
                int ar = wr * 64 + m * 16 + (lane & 15);                        \
                af[m] = *(const short8*)&Ab_[ar]                                \
                            [swzk(kk * 32 + (lane >> 4) * 8, ar)];              \
            }                                                                   \
            _Pragma("unroll")                                                   \
            for (int n = 0; n < 4; n++) {                                       \
                int br = wc * 64 + n * 16 + (lane & 15);                        \
                bq[n] = *(const short8*)&Bb_[br]                                \
                            [swzk(kk * 32 + (lane >> 4) * 8, br)];              \
            }                                                                   \
            _Pragma("unroll")                                                   \
            for (int m = 0; m < 4; m++)                                         \
                _Pragma("unroll")                                               \
                for (int n = 0; n < 4; n++)                                     \
                    acc[m][n] = __builtin_amdgcn_mfma_f32_16x16x32_bf16(        \
                        af[m], bq[n], acc[m][n], 0, 0, 0);                      \
        }                                                                       \
    } while (0)

// ---------------------------------------------------------------------------
// gemm_lds: C = A[M][K] * Bt[N][K]^T, A/Bt bf16 row-major PRE-SWIZZLED,
// lda = ldbt = 8192. 2-phase double-buffered global_load_lds staging.
// EPI: 0 = f32 store, 2 = bf16 row-major store, 3 = f32 atomicAdd.
// kcount/64 EVEN. grid z = k-split.
// ---------------------------------------------------------------------------
template <int EPI, int SWZX>
__launch_bounds__(256)
__global__ void gemm_lds(const short* __restrict__ A, const short* __restrict__ Bt,
                         void* __restrict__ C, int ldc, int kcount) {
    __shared__ short As0[128][64], Bs0[128][64];
    __shared__ short As1[128][64], Bs1[128][64];
    int bx = blockIdx.x, by = blockIdx.y;
    if (SWZX) {
        int lid = blockIdx.x + blockIdx.y * 8;
        int c = lid & 7, s = lid >> 3;
        by = c * 8 + (s >> 3);
        bx = s & 7;
    }
    const int tid  = threadIdx.x;
    const int lane = tid & 63;
    const int w    = tid >> 6;
    const int wr   = w >> 1, wc = w & 1;
    const int i0   = by * 128;
    const int n0   = bx * 128;
    const int k0   = blockIdx.z * kcount;

    const int srow = w * 32 + (lane >> 3);
    const short* gA = A  + (size_t)(i0 + srow) * 8192 + k0 + (lane & 7) * 8;
    const short* gB = Bt + (size_t)(n0 + srow) * 8192 + k0 + (lane & 7) * 8;

    f32x4 acc[4][4];
    #pragma unroll
    for (int m = 0; m < 4; m++)
        #pragma unroll
        for (int n = 0; n < 4; n++) acc[m][n] = (f32x4){0.f, 0.f, 0.f, 0.f};

#define STAGE_TILE(ts, Ab, Bb)                                                  \
    do {                                                                        \
        _Pragma("unroll")                                                       \
        for (int j = 0; j < 4; j++) {                                           \
            gload16(gA + (size_t)(ts) * 64 + (size_t)j * 8 * 8192,              \
                    &Ab[w * 32 + j * 8][0]);                                    \
            gload16(gB + (size_t)(ts) * 64 + (size_t)j * 8 * 8192,              \
                    &Bb[w * 32 + j * 8][0]);                                    \
        }                                                                       \
    } while (0)

    const int nt = kcount >> 6;            // even at every call site
    STAGE_TILE(0, As0, Bs0);
    for (int t = 0; t < nt; t += 2) {
        __syncthreads();
        STAGE_TILE(t + 1, As1, Bs1);
        MFMA_COMPUTE(As0, Bs0);
        __syncthreads();
        if (t + 2 < nt) STAGE_TILE(t + 2, As0, Bs0);
        MFMA_COMPUTE(As1, Bs1);
    }
#undef STAGE_TILE

    #pragma unroll
    for (int m = 0; m < 4; m++) {
        #pragma unroll
        for (int n = 0; n < 4; n++) {
            int row0 = i0 + wr * 64 + m * 16 + ((lane >> 4) << 2);
            int col  = n0 + wc * 64 + n * 16 + (lane & 15);
            #pragma unroll
            for (int r = 0; r < 4; r++) {
                float v = acc[m][n][r];
                if (EPI == 0)      ((float*)C)[(size_t)(row0 + r) * ldc + col] = v;
                else if (EPI == 2) ((short*)C)[(size_t)(row0 + r) * ldc + col] = f2bf(v);
                else atomicAdd(&((float*)C)[(size_t)(row0 + r) * ldc + col], v);
            }
        }
    }
}

// ---------------------------------------------------------------------------
// gemm_gen: C = gen(mask)[M][K] * Bt[N][K]^T with
// a_ik = bit_ik * max(E1[i]E2[k], F1[i]F2[k]). Mask bits from adjm; A staged
// to LDS swizzled. B via global_load_lds. EPI=3 atomicAdd. kcount/64 EVEN.
// (Use ONLY where the A-panel is consumed by ONE n-block — R12 lesson.)
// ---------------------------------------------------------------------------
template <int EPI, int SWZX>
__launch_bounds__(256)
__global__ void gemm_gen(const unsigned char* __restrict__ adjm,
                         const short* __restrict__ Bt,
                         float* __restrict__ C, int ldc, int kcount,
                         const float* __restrict__ E1, const float* __restrict__ F1,
                         const float* __restrict__ E2, const float* __restrict__ F2) {
    __shared__ short As0[128][64], Bs0[128][64];
    __shared__ short As1[128][64], Bs1[128][64];
    int bx = blockIdx.x, by = blockIdx.y;
    if (SWZX) {
        int lid = blockIdx.x + blockIdx.y * 8;
        int c = lid & 7, s = lid >> 3;
        by = c * 8 + (s >> 3);
        bx = s & 7;
    }
    const int tid  = threadIdx.x;
    const int lane = tid & 63;
    const int w    = tid >> 6;
    const int wr   = w >> 1, wc = w & 1;
    const int i0   = by * 128;
    const int n0   = bx * 128;
    const int k0   = blockIdx.z * kcount;

    const int srow = w * 32 + (lane >> 3);
    const short* gB = Bt + (size_t)(n0 + srow) * 8192 + k0 + (lane & 7) * 8;
    const int mr = tid >> 1, mh = tid & 1;        // staging row / k-half
    const unsigned char* gM = adjm + (size_t)(i0 + mr) * 1024 + (k0 >> 3) + mh * 4;
    const float e1v = E1[i0 + mr], f1v = F1[i0 + mr];

    f32x4 acc[4][4];
    #pragma unroll
    for (int m = 0; m < 4; m++)
        #pragma unroll
        for (int n = 0; n < 4; n++) acc[m][n] = (f32x4){0.f, 0.f, 0.f, 0.f};

    unsigned mreg;   // 32 mask bits for (mr, k-half)

#define G_ALOAD(ts)                                                             \
    do { mreg = *(const unsigned*)(gM + (size_t)(ts) * 8); } while (0)

#define G_BLOAD(ts, Bb)                                                         \
    do {                                                                        \
        _Pragma("unroll")                                                       \
        for (int j = 0; j < 4; j++)                                             \
            gload16(gB + (size_t)(ts) * 64 + (size_t)j * 8 * 8192,              \
                    &Bb[w * 32 + j * 8][0]);                                    \
    } while (0)

#define G_WSTAGE(ts, As_)                                                       \
    do {                                                                        \
        _Pragma("unroll")                                                       \
        for (int b = 0; b < 4; b++) {                                           \
            int kbr = mh * 4 + b;                                               \
            int rk = k0 + (ts) * 64 + kbr * 8;                                  \
            unsigned mbyte = (mreg >> (8 * b)) & 0xFFu;                         \
            f32x4 e2a = *(const f32x4*)(E2 + rk);                               \
            f32x4 e2b = *(const f32x4*)(E2 + rk + 4);                           \
            f32x4 f2a = *(const f32x4*)(F2 + rk);                               \
            f32x4 f2b = *(const f32x4*)(F2 + rk + 4);                           \
            short8 p;                                                           \
            _Pragma("unroll")                                                   \
            for (int e = 0; e < 8; e++) {                                       \
                float ev = e < 4 ? e2a[e] : e2b[e - 4];                         \
                float fv = e < 4 ? f2a[e] : f2b[e - 4];                         \
                float wg = fmaxf(e1v * ev, f1v * fv);                           \
                p[e] = ((mbyte >> e) & 1) ? f2bf(wg) : (short)0;                \
            }                                                                   \
            *(short8*)&As_[mr][(kbr ^ sfun(mr)) * 8] = p;                       \
        }                                                                       \
    } while (0)

    const int nt = kcount >> 6;            // even
    G_ALOAD(0);
    G_BLOAD(0, Bs0);
    for (int t = 0; t < nt; t += 2) {
        G_WSTAGE(t, As0);
        __syncthreads();
        G_ALOAD(t + 1);
        G_BLOAD(t + 1, Bs1);
        MFMA_COMPUTE(As0, Bs0);
        G_WSTAGE(t + 1, As1);
        __syncthreads();
        if (t + 2 < nt) { G_ALOAD(t + 2); G_BLOAD(t + 2, Bs0); }
        MFMA_COMPUTE(As1, Bs1);
    }
#undef G_ALOAD
#undef G_BLOAD
#undef G_WSTAGE

    #pragma unroll
    for (int m = 0; m < 4; m++) {
        #pragma unroll
        for (int n = 0; n < 4; n++) {
            int row0 = i0 + wr * 64 + m * 16 + ((lane >> 4) << 2);
            int col  = n0 + wc * 64 + n * 16 + (lane & 15);
            #pragma unroll
            for (int r = 0; r < 4; r++)
                atomicAdd(&C[(size_t)(row0 + r) * ldc + col], acc[m][n][r]);
        }
    }
}

// ---------------------------------------------------------------------------
// gemm_maskb: C^T = (bin(mask)[M][K] @ Bt[N][K]^T)^T. Binary A expanded via a
// 4 KB LDS LUT (byte -> 8 bf16). B via global_load_lds. Output bf16
// transposed-swizzled (ld 8192). K = 8192 (nt = 128).
// ---------------------------------------------------------------------------
template <int SWZX>
__launch_bounds__(256)
__global__ void gemm_maskb(const unsigned char* __restrict__ adjm,
                           const short* __restrict__ Bt,
                           short* __restrict__ C) {
    __shared__ short As0[128][64], Bs0[128][64];
    __shared__ short As1[128][64], Bs1[128][64];
    __shared__ __align__(16) short lutb[256][8];   // byte -> 8 bf16 (0 / 1.0)
    int bx = blockIdx.x, by = blockIdx.y;
    if (SWZX) {
        int lid = blockIdx.x + blockIdx.y * 8;
        int c = lid & 7, s = lid >> 3;
        by = c * 8 + (s >> 3);
        bx = s & 7;
    }
    const int tid  = threadIdx.x;
    const int lane = tid & 63;
    const int w    = tid >> 6;
    const int wr   = w >> 1, wc = w & 1;
    const int i0   = by * 128;
    const int n0   = bx * 128;

    const int srow = w * 32 + (lane >> 3);
    const short* gB = Bt + (size_t)(n0 + srow) * 8192 + (lane & 7) * 8;
    const int mr = tid >> 1, mh = tid & 1;
    const unsigned char* gM = adjm + (size_t)(i0 + mr) * 1024 + mh * 4;

    // build LUT (each thread fills its own 16B entry)
    {
        short8 ent;
        #pragma unroll
        for (int e = 0; e < 8; e++)
            ent[e] = ((tid >> e) & 1) ? (short)0x3F80 : (short)0;
        *(short8*)&lutb[tid][0] = ent;
    }

    f32x4 acc[4][4];
    #pragma unroll
    for (int m = 0; m < 4; m++)
        #pragma unroll
        for (int n = 0; n < 4; n++) acc[m][n] = (f32x4){0.f, 0.f, 0.f, 0.f};

#define MB_BLOAD(ts, Bb)                                                        \
    do {                                                                        \
        _Pragma("unroll")                                                       \
        for (int j = 0; j < 4; j++)                                             \
            gload16(gB + (size_t)(ts) * 64 + (size_t)j * 8 * 8192,              \
                    &Bb[w * 32 + j * 8][0]);                                    \
    } while (0)

#define MB_WSTAGE(As_, mrg)                                                     \
    do {                                                                        \
        _Pragma("unroll")                                                       \
        for (int b = 0; b < 4; b++) {                                           \
            int kbr = mh * 4 + b;                                               \
            unsigned mbyte = ((mrg) >> (8 * b)) & 0xFFu;                        \
            short8 p = *(const short8*)&lutb[mbyte][0];                         \
            *(short8*)&As_[mr][(kbr ^ sfun(mr)) * 8] = p;                       \
        }                                                                       \
    } while (0)

    const int nt = 128;                    // K = 8192
    unsigned mreg = *(const unsigned*)(gM);
    MB_BLOAD(0, Bs0);
    __syncthreads();                       // LUT visible to all waves
    for (int t = 0; t < nt; t += 2) {
        MB_WSTAGE(As0, mreg);
        __syncthreads();
        unsigned mnext = *(const unsigned*)(gM + (size_t)(t + 1) * 8);
        MB_BLOAD(t + 1, Bs1);
        MFMA_COMPUTE(As0, Bs0);
        MB_WSTAGE(As1, mnext);
        __syncthreads();
        if (t + 2 < nt) {
            mreg = *(const unsigned*)(gM + (size_t)(t + 2) * 8);
            MB_BLOAD(t + 2, Bs0);
        }
        MFMA_COMPUTE(As1, Bs1);
    }
#undef MB_BLOAD
#undef MB_WSTAGE

    // transposed-swizzled bf16 epilogue (C^T)
    #pragma unroll
    for (int m = 0; m < 4; m++) {
        #pragma unroll
        for (int n = 0; n < 4; n++) {
            int row0 = i0 + wr * 64 + m * 16 + ((lane >> 4) << 2);
            int col  = n0 + wc * 64 + n * 16 + (lane & 15);
            unsigned long long pk = 0;
            #pragma unroll
            for (int r = 0; r < 4; r++)
                pk |= (unsigned long long)(unsigned short)f2bf(acc[m][n][r])
                      << (16 * r);
            *(unsigned long long*)(C + (size_t)col * 8192 + swzk(row0, col)) = pk;
        }
    }
}

// ---------------------------------------------------------------------------
// gemm_xw_k: C[M][N]=A[M][256]@B[256][N], A,B f32. Dual-write epilogue:
// C row-major bf16 (ld=N) + Ct = C^T bf16 swizzled (ld=8192).
// ---------------------------------------------------------------------------
template <int SWZX>
__launch_bounds__(256)
__global__ void gemm_xw_k(const float* __restrict__ A, const float* __restrict__ B,
                          short* __restrict__ C, short* __restrict__ Ct, int ldn) {
    __shared__ short As[128][64];
    __shared__ short Bs[128][64];
    int bx = blockIdx.x, by = blockIdx.y;
    if (SWZX) {
        int lid = blockIdx.x + blockIdx.y * 8;
        int c = lid & 7, s = lid >> 3;
        by = c * 8 + (s >> 3);
        bx = s & 7;
    }
    const int tid  = threadIdx.x;
    const int lane = tid & 63;
    const int w    = tid >> 6;
    const int wr   = w >> 1, wc = w & 1;
    const int i0   = by * 128;
    const int n0   = bx * 128;

    f32x4 acc[4][4];
    #pragma unroll
    for (int m = 0; m < 4; m++)
        #pragma unroll
        for (int n = 0; n < 4; n++) acc[m][n] = (f32x4){0.f, 0.f, 0.f, 0.f};

    for (int ks = 0; ks < 256; ks += 64) {
        __syncthreads();
        #pragma unroll
        for (int it = 0; it < 4; it++) {
            int idx = it * 256 + tid;
            int cg = idx & 7, r = idx >> 3;
            *(short8*)&As[r][swzk(cg * 8, r)] =
                ld8<1>(A, (size_t)(i0 + r) * 256 + ks + cg * 8);
        }
        #pragma unroll
        for (int it = 0; it < 2; it++) {
            int idx = it * 256 + tid;
            int ng = idx & 15, kp = idx >> 4;
            int k = 2 * kp;
            short8 r0 = ld8<1>(B, (size_t)(ks + k) * ldn + n0 + ng * 8);
            short8 r1 = ld8<1>(B, (size_t)(ks + k + 1) * ldn + n0 + ng * 8);
            #pragma unroll
            for (int j = 0; j < 8; j++) {
                int row = ng * 8 + j;
                *(unsigned*)&Bs[row][swzk(k, row)] = pack2(r0[j], r1[j]);
            }
        }
        __syncthreads();
        MFMA_COMPUTE(As, Bs);
    }
    #pragma unroll
    for (int m = 0; m < 4; m++) {
        #pragma unroll
        for (int n = 0; n < 4; n++) {
            int row0 = i0 + wr * 64 + m * 16 + ((lane >> 4) << 2);
            int col  = n0 + wc * 64 + n * 16 + (lane & 15);
            unsigned long long pk = 0;
            #pragma unroll
            for (int r = 0; r < 4; r++) {
                short b = f2bf(acc[m][n][r]);
                C[(size_t)(row0 + r) * ldn + col] = b;
                pk |= (unsigned long long)(unsigned short)b << (16 * r);
            }
            *(unsigned long long*)(Ct + (size_t)col * 8192 + swzk(row0, col)) = pk;
        }
    }
}

// f-dots + E/F vectors fused: per row, f = h.a dots; E = exp(f), F = exp(0.2f)
__launch_bounds__(256)
__global__ void compute_f_k(const short* __restrict__ h1, const short* __restrict__ h2,
                            const float* __restrict__ ae, const float* __restrict__ aa,
                            float* __restrict__ E11, float* __restrict__ F11,
                            float* __restrict__ E21, float* __restrict__ F21,
                            float* __restrict__ E12, float* __restrict__ F12,
                            float* __restrict__ E22, float* __restrict__ F22) {
    int row = blockIdx.x, t = threadIdx.x;
    float s11 = 0.f, s21 = 0.f, s12 = 0.f, s22 = 0.f;
    if (t < 128) {
        float hv = bf2f(h1[(size_t)row * 128 + t]);
        s11 = hv * ae[t];
        s21 = hv * ae[128 + t];
    }
    #pragma unroll
    for (int q = 0; q < 4; q++) {
        int f = t + q * 256;
        float hv = bf2f(h2[(size_t)row * 1024 + f]);
        s12 += hv * aa[f];
        s22 += hv * aa[1024 + f];
    }
    __shared__ float red[4][4];
    s11 = wred_sum(s11); s21 = wred_sum(s21);
    s12 = wred_sum(s12); s22 = wred_sum(s22);
    int w = t >> 6;
    if ((t & 63) == 0) { red[0][w] = s11; red[1][w] = s21; red[2][w] = s12; red[3][w] = s22; }
    __syncthreads();
    if (t == 0) {
        float a = red[0][0] + red[0][1] + red[0][2] + red[0][3];
        float b = red[1][0] + red[1][1] + red[1][2] + red[1][3];
        float c = red[2][0] + red[2][1] + red[2][2] + red[2][3];
        float d = red[3][0] + red[3][1] + red[3][2] + red[3][3];
        E11[row] = __expf(a); F11[row] = __expf(0.2f * a);
        E21[row] = __expf(b); F21[row] = __expf(0.2f * b);
        E12[row] = __expf(c); F12[row] = __expf(0.2f * c);
        E22[row] = __expf(d); F22[row] = __expf(0.2f * d);
    }
}

// One adj pass, 8 rows/block: den1/den2 + P2b (swizzled bf16) + adjm (bitmask).
// E/F vector loads amortized across the 8 rows.
__launch_bounds__(256)
__global__ void prepass_k(const float* __restrict__ adj,
                          const float* __restrict__ E11, const float* __restrict__ F11,
                          const float* __restrict__ E21, const float* __restrict__ F21,
                          const float* __restrict__ E12, const float* __restrict__ F12,
                          const float* __restrict__ E22, const float* __restrict__ F22,
                          float* __restrict__ den1, float* __restrict__ den2,
                          short* __restrict__ P2b, unsigned char* __restrict__ adjm) {
    const int r0 = blockIdx.x * 8, t = threadIdx.x;
    float e1r[8], f1r[8], e2r[8], f2r[8];
    #pragma unroll
    for (int r = 0; r < 8; r++) {
        e1r[r] = E11[r0 + r]; f1r[r] = F11[r0 + r];
        e2r[r] = E12[r0 + r]; f2r[r] = F12[r0 + r];
    }
    float d1[8], d2[8];
    #pragma unroll
    for (int r = 0; r < 8; r++) { d1[r] = 0.f; d2[r] = 0.f; }
    #pragma unroll
    for (int jc = 0; jc < 4; jc++) {
        int jb = jc * 2048 + t * 8;
        f32x4 eA0 = *(const f32x4*)(E21 + jb), eA1 = *(const f32x4*)(E21 + jb + 4);
        f32x4 fA0 = *(const f32x4*)(F21 + jb), fA1 = *(const f32x4*)(F21 + jb + 4);
        f32x4 eB0 = *(const f32x4*)(E22 + jb), eB1 = *(const f32x4*)(E22 + jb + 4);
        f32x4 fB0 = *(const f32x4*)(F22 + jb), fB1 = *(const f32x4*)(F22 + jb + 4);
        #pragma unroll
        for (int r = 0; r < 8; r++) {
            const float* ap = adj + (size_t)(r0 + r) * 8192 + jb;
            f32x4 a0 = *(const f32x4*)ap, a1 = *(const f32x4*)(ap + 4);
            short8 p2v;
            unsigned mb = 0;
            #pragma unroll
            for (int e = 0; e < 8; e++) {
                float av = e < 4 ? a0[e] : a1[e - 4];
                float eA = e < 4 ? eA0[e] : eA1[e - 4];
                float fA = e < 4 ? fA0[e] : fA1[e - 4];
                float eB = e < 4 ? eB0[e] : eB1[e - 4];
                float fB = e < 4 ? fB0[e] : fB1[e - 4];
                float x1 = fmaxf(e1r[r] * eA, f1r[r] * fA);  // exp(lrelu(f1+f2))
                float x2 = fmaxf(e2r[r] * eB, f2r[r] * fB);
                bool on = av > 0.f;
                d1[r] += on ? x1 : 0.f;
                d2[r] += on ? x2 : 0.f;
                p2v[e] = on ? f2bf(x2) : (short)0;
                mb |= (on ? 1u : 0u) << e;
            }
            *(short8*)(P2b + (size_t)(r0 + r) * 8192 + swzk(jb, r0 + r)) = p2v;
            adjm[(size_t)(r0 + r) * 1024 + (jb >> 3)] = (unsigned char)mb;
        }
    }
    __shared__ float r1s[4][8], r2s[4][8];   // [wave][row]
    #pragma unroll
    for (int r = 0; r < 8; r++) { d1[r] = wred_sum(d1[r]); d2[r] = wred_sum(d2[r]); }
    if ((t & 63) == 0) {
        #pragma unroll
        for (int r = 0; r < 8; r++) { r1s[t >> 6][r] = d1[r]; r2s[t >> 6][r] = d2[r]; }
    }
    __syncthreads();
    if (t < 8) {
        den1[r0 + t] = r1s[0][t] + r1s[1][t] + r1s[2][t] + r1s[3][t];
        den2[r0 + t] = r2s[0][t] + r2s[1][t] + r2s[2][t] + r2s[3][t];
    }
}

// zlt = transpose(elu(Y1/den1 + h1)) swizzled, fused. Block = 64 rows x 128 cols.
__launch_bounds__(256)
__global__ void epi_gat1t_k(const float* __restrict__ Y1, const float* __restrict__ den1,
                            const short* __restrict__ h1, short* __restrict__ zlt) {
    __shared__ short ts[128][65];
    int tr = blockIdx.x * 64;
    int t = threadIdx.x;
    #pragma unroll
    for (int it = 0; it < 4; it++) {
        int idx = it * 256 + t;
        int r = idx >> 4, cb = idx & 15;
        int row = tr + r;
        float d = den1[row]; d = d > 0.f ? d : 1.f;
        const float* yp = Y1 + (size_t)row * 128 + cb * 8;
        f32x4 y0 = *(const f32x4*)yp, y1 = *(const f32x4*)(yp + 4);
        short8 hv = *(const short8*)(h1 + (size_t)row * 128 + cb * 8);
        #pragma unroll
        for (int e = 0; e < 8; e++) {
            float z = (e < 4 ? y0[e] : y1[e - 4]) / d + bf2f(hv[e]);
            z = z > 0.f ? z : (__expf(z) - 1.f);
            ts[cb * 8 + e][r] = f2bf(z);
        }
    }
    __syncthreads();
    #pragma unroll
    for (int it = 0; it < 4; it++) {
        int idx = it * 256 + t;
        int c = idx >> 3, rb = idx & 7;
        short8 v = *(const short8*)&ts[c][rb * 8];
        *(short8*)(zlt + (size_t)c * 8192 + tr + ((rb ^ sfun(c)) << 3)) = v;
    }
}

// s_l row = softmax( elu(Y2/den2 + h2) ). Y2 is bf16. f32 to d_out, bf16 to ws.
__launch_bounds__(256)
__global__ void episoft_k(const short* __restrict__ Y2, const float* __restrict__ den2,
                          const short* __restrict__ h2, float* __restrict__ slo,
                          short* __restrict__ slb) {
    int row = blockIdx.x, t = threadIdx.x;
    float d = den2[row];
    d = d > 0.f ? d : 1.f;
    float inv_d = 1.f / d;
    float v[4], mx = -1e30f;
    #pragma unroll
    for (int q = 0; q < 4; q++) {
        int j = t + q * 256;
        float a = bf2f(Y2[(size_t)row * 1024 + j]) * inv_d +
                  bf2f(h2[(size_t)row * 1024 + j]);
        a = a > 0.f ? a : (__expf(a) - 1.f);
        v[q] = a;
        mx = fmaxf(mx, a);
    }
    __shared__ float sred[4];
    __shared__ float sbc;
    mx = wred_max(mx);
    if ((t & 63) == 0) sred[t >> 6] = mx;
    __syncthreads();
    if (t == 0) sbc = fmaxf(fmaxf(sred[0], sred[1]), fmaxf(sred[2], sred[3]));
    __syncthreads();
    mx = sbc;
    float s = 0.f;
    #pragma unroll
    for (int q = 0; q < 4; q++) { v[q] = __expf(v[q] - mx); s += v[q]; }
    s = wred_sum(s);
    if ((t & 63) == 0) sred[t >> 6] = s;
    __syncthreads();
    if (t == 0) sbc = sred[0] + sred[1] + sred[2] + sred[3];
    __syncthreads();
    float inv = 1.f / sbc;
    #pragma unroll
    for (int q = 0; q < 4; q++) {
        float sv = v[q] * inv;
        slo[(size_t)row * 1024 + t + q * 256] = sv;
        slb[(size_t)row * 1024 + t + q * 256] = f2bf(sv);
    }
}

// tiled transpose: in [R][C] bf16 -> out [C][R] bf16, swizzled blocks
template <int F32IN>
__launch_bounds__(256)
__global__ void transpose_swz_k(const void* __restrict__ in, short* __restrict__ out,
                                int R, int C) {
    __shared__ short ts[64][72];
    int tc = blockIdx.x * 64;
    int tr = blockIdx.y * 64;
    int t = threadIdx.x;
    #pragma unroll
    for (int h = 0; h < 2; h++) {
        int r = (t >> 3) + h * 32, c = (t & 7) * 8;
        *(short8*)&ts[r][c] = ld8<F32IN>(in, (size_t)(tr + r) * C + tc + c);
    }
    __syncthreads();
    #pragma unroll
    for (int h = 0; h < 2; h++) {
        int n = t >> 2, blk = (t & 3) + h * 4;
        short8 v;
        #pragma unroll
        for (int e = 0; e < 8; e++) v[e] = ts[blk * 8 + e][n];
        *(short8*)(out + (size_t)(tc + n) * R + tr + ((blk ^ sfun(tc + n)) << 3)) = v;
    }
}

extern "C" void kernel_launch(void* const* d_in, const int* in_sizes, int n_in,
                              void* d_out, int out_size, void* d_ws, size_t ws_size,
                              hipStream_t stream) {
    const float* x   = (const float*)d_in[0];  // [8192,256]
    const float* adj = (const float*)d_in[1];  // [8192,8192]
    const float* We  = (const float*)d_in[2];  // [256,128]
    const float* ae  = (const float*)d_in[3];  // [256]
    const float* Wa  = (const float*)d_in[4];  // [256,1024]
    const float* aa  = (const float*)d_in[5];  // [2048]
    float* out = (float*)d_out;

    char* w = (char*)d_ws;                       // 264 MiB used
    short* h1b = (short*)(w);                    // 0..2M    bf16 [8192,128]
    short* h2b = (short*)(w + (2u   << 20));     // 2..18M   bf16 [8192,1024]
    float* E11 = (float*)(w + (18u  << 20));     // 18..19M  vectors
    float* F11 = E11 + 8192;  float* E21 = F11 + 8192; float* F21 = E21 + 8192;
    float* E12 = F21 + 8192;  float* F12 = E12 + 8192;
    float* E22 = F12 + 8192;  float* F22 = E22 + 8192;
    float* den1 = F22 + 8192; float* den2 = den1 + 8192;
    float* Y1f = (float*)(w + (21u << 20));      // 21..25M  f32  [8192,128]
    short* Y2b = (short*)(w + (25u << 20));      // 25..41M  bf16 [8192,1024]
    short* slb = (short*)(w + (57u << 20));      // 57..73M  bf16 [8192,1024]
    short* h1t = (short*)(w + (73u << 20));      // 73..75M  bf16 [128,8192]  swz
    short* h2t = (short*)(w + (75u << 20));      // 75..91M  bf16 [1024,8192] swz
    short* slt = (short*)(w + (91u << 20));      // 91..107M bf16 [1024,8192] swz
    short* zlt = (short*)(w + (107u << 20));     // 107..109M bf16 [128,8192] swz
    short* tT  = (short*)(w + (109u << 20));     // 109..125M bf16 [1024,8192] swz
    short* P2b = (short*)(w + (128u << 20));     // 128..256M bf16 [8192,8192] swz
    unsigned char* adjm = (unsigned char*)(w + (256u << 20)); // 8 MiB bitmask

    float* xo  = out;                            // xnext [1024,128]
    float* ao  = out + 131072;                   // anext [1024,1024]
    float* slo = out + 131072 + 1048576;         // s_l   [8192,1024]

    hipMemsetAsync(out, 0, (size_t)(131072 + 1048576) * 4, stream);
    hipMemsetAsync(Y1f, 0, (size_t)8192 * 128 * 4, stream);

    // h1 = x@We ; h2 = x@Wa  (dual write: row-major + transposed-swizzled)
    gemm_xw_k<0><<<dim3(1, 64), 256, 0, stream>>>(x, We, h1b, h1t, 128);
    gemm_xw_k<1><<<dim3(8, 64), 256, 0, stream>>>(x, Wa, h2b, h2t, 1024);
    compute_f_k<<<dim3(8192), 256, 0, stream>>>(h1b, h2b, ae, aa,
        E11, F11, E21, F21, E12, F12, E22, F22);
    prepass_k<<<dim3(1024), 256, 0, stream>>>(adj,
        E11, F11, E21, F21, E12, F12, E22, F22, den1, den2, P2b, adjm);

    // Y1 = (mask .* w1) @ h1 (gen-GEMM, split-K x8, atomics into Y1f)
    gemm_gen<3, 0><<<dim3(1, 64, 8), 256, 0, stream>>>(
        adjm, h1t, Y1f, 128, 1024, E11, F11, E21, F21);
    epi_gat1t_k<<<dim3(128), 256, 0, stream>>>(Y1f, den1, h1b, zlt);

    // Y2 = P2 @ h2 (gload GEMM, unsplit, bf16 store)
    gemm_lds<2, 1><<<dim3(8, 64, 1), 256, 0, stream>>>(P2b, h2t, Y2b, 1024, 8192);
    episoft_k<<<dim3(8192), 256, 0, stream>>>(Y2b, den2, h2b, slo, slb);
    transpose_swz_k<0><<<dim3(16, 128), 256, 0, stream>>>(slb, slt, 8192, 1024);

    // tT = (mask @ s_l)^T  (LUT-expanded binary A, fused transpose)
    gemm_maskb<1><<<dim3(8, 64), 256, 0, stream>>>(adjm, slt, tT);

    // anext = s_l^T @ t ; xnext = s_l^T @ z_l  (atomics into d_out)
    gemm_lds<3, 0><<<dim3(8, 8, 8), 256, 0, stream>>>(slt, tT, ao, 1024, 1024);
    gemm_lds<3, 0><<<dim3(1, 8, 32), 256, 0, stream>>>(slt, zlt, xo, 128, 256);
}